// Round 1
// baseline (3438.245 us; speedup 1.0000x reference)
//
#include <hip/hip_runtime.h>
#include <hip/hip_bf16.h>
#include <math.h>

#define B 32
#define CFULL 12
#define CH 6
#define HH 128
#define WW 128
#define HID 128
#define CO3 54
#define NB 5
#define OUT_ELEMS (B*CFULL*HH*WW)

// ---------------- init objective ----------------
__global__ void k_init_obj(const float* __restrict__ obj_in, float* __restrict__ obj_out) {
    int i = threadIdx.x;
    if (i < B) obj_out[i] = obj_in[i];
}

// ---------------- conv1(3x3,6->128)+relu fused with conv2(1x1,128->128)+relu ----------------
__global__ __launch_bounds__(256) void k_conv12(
    const float* __restrict__ x,
    const float* __restrict__ w1, const float* __restrict__ b1,
    const float* __restrict__ w2, const float* __restrict__ b2,
    float* __restrict__ h2)
{
    __shared__ float xs[CH][3][132];      // input rows, width 130 used (1-pad each side)
    __shared__ float h1row[HID][HH];      // [co][w]

    const int b = blockIdx.x >> 7;
    const int h = blockIdx.x & 127;
    const int tid = threadIdx.x;

    // stage input rows (channels 0..5 = identity half feeds the net)
    for (int i = tid; i < CH*3*130; i += 256) {
        int ci = i / 390; int rem = i - ci*390;
        int r = rem / 130; int xw = rem - r*130;
        int hh = h + r - 1, ww = xw - 1;
        float v = 0.f;
        if (hh >= 0 && hh < HH && ww >= 0 && ww < WW)
            v = x[((b*CFULL + ci)*HH + hh)*WW + ww];
        xs[ci][r][xw] = v;
    }
    __syncthreads();

    const int w  = tid & 127;
    const int cog = __builtin_amdgcn_readfirstlane(tid >> 7);   // 0..1, wave-uniform

    // register patch: 6ci x 3r x 3dx
    float p[54];
#pragma unroll
    for (int ci = 0; ci < CH; ++ci)
#pragma unroll
        for (int r = 0; r < 3; ++r)
#pragma unroll
            for (int dx = 0; dx < 3; ++dx)
                p[(ci*3+r)*3+dx] = xs[ci][r][w + dx];

    // conv1: each thread computes 64 output channels for its pixel
    for (int k = 0; k < 64; ++k) {
        int co = cog*64 + k;                       // wave-uniform
        const float* wp = w1 + co*54;
        float acc = b1[co];
#pragma unroll
        for (int s = 0; s < 54; ++s) acc = fmaf(wp[s], p[s], acc);
        h1row[co][w] = fmaxf(acc, 0.f);
    }
    __syncthreads();

    // conv2 (1x1): acc 8 cos at a time, x from LDS (lane-contiguous b32)
    for (int k0 = 0; k0 < 64; k0 += 8) {
        int cob = cog*64 + k0;                     // wave-uniform
        float acc[8];
#pragma unroll
        for (int j = 0; j < 8; ++j) acc[j] = b2[cob + j];
        for (int ci = 0; ci < HID; ci += 4) {
            float x0 = h1row[ci  ][w];
            float x1 = h1row[ci+1][w];
            float x2 = h1row[ci+2][w];
            float x3 = h1row[ci+3][w];
#pragma unroll
            for (int j = 0; j < 8; ++j) {
                const float* wr = w2 + (cob + j)*HID + ci;
                acc[j] = fmaf(wr[0], x0, acc[j]);
                acc[j] = fmaf(wr[1], x1, acc[j]);
                acc[j] = fmaf(wr[2], x2, acc[j]);
                acc[j] = fmaf(wr[3], x3, acc[j]);
            }
        }
#pragma unroll
        for (int j = 0; j < 8; ++j)
            h2[((b*HID + cob + j)*HH + h)*WW + w] = fmaxf(acc[j], 0.f);
    }
}

// ---------------- conv3(3x3,128->54) + spline + identity copy + objective ----------------
__global__ __launch_bounds__(512) void k_conv3_spline(
    const float* __restrict__ x,
    const float* __restrict__ h2,
    const float* __restrict__ w3, const float* __restrict__ b3,
    float* __restrict__ out, float* __restrict__ obj)
{
    __shared__ float xs2[HID*3*66];     // [ci][r][66] input tile; later reused for params [54][66]
    __shared__ float red[8];

    const int w0 = blockIdx.x * 64;
    const int h  = blockIdx.y;
    const int b  = blockIdx.z;
    const int tid = threadIdx.x;

    for (int i = tid; i < HID*3*66; i += 512) {
        int ci = i / 198; int rem = i - ci*198;
        int r = rem / 66; int xw = rem - r*66;
        int hh = h + r - 1, ww = w0 + xw - 1;
        float v = 0.f;
        if (hh >= 0 && hh < HH && ww >= 0 && ww < WW)
            v = h2[((b*HID + ci)*HH + hh)*WW + ww];
        xs2[i] = v;
    }
    __syncthreads();

    const int wp  = tid & 63;
    const int cog = __builtin_amdgcn_readfirstlane(tid >> 6);   // 0..7, wave-uniform

    float acc[7];
#pragma unroll
    for (int k = 0; k < 7; ++k) acc[k] = 0.f;

    for (int ci0 = 0; ci0 < HID; ci0 += 8) {
        float p[72];
#pragma unroll
        for (int cc = 0; cc < 8; ++cc)
#pragma unroll
            for (int r = 0; r < 3; ++r)
#pragma unroll
                for (int dx = 0; dx < 3; ++dx)
                    p[(cc*3+r)*3+dx] = xs2[((ci0+cc)*3 + r)*66 + wp + dx];
#pragma unroll
        for (int k = 0; k < 7; ++k) {
            int co = cog + 8*k;                    // wave-uniform
            if (co < CO3) {
                const float* wr = w3 + (co*HID + ci0)*9;
#pragma unroll
                for (int s = 0; s < 72; ++s) acc[k] = fmaf(wr[s], p[s], acc[k]);
            }
        }
    }
    __syncthreads();                // all conv reads of xs2 done

    // params tile [54][66] reusing xs2
    float* pl = xs2;
#pragma unroll
    for (int k = 0; k < 7; ++k) {
        int co = cog + 8*k;
        if (co < CO3) pl[co*66 + wp] = acc[k] + b3[co];
    }
    __syncthreads();

    // spline + identity copy: threads 0..383, c = tid>>6 (wave-uniform), px = wp
    float lad = 0.f;
    if (tid < 384) {
        const int c = tid >> 6;
        const int px = wp;
        // identity copy (channels 0..5)
        {
            float idv = x[((b*CFULL + c)*HH + h)*WW + w0 + px];
            out[((b*CFULL + c)*HH + h)*WW + w0 + px] = idv;
        }
        float u[9];
#pragma unroll
        for (int j = 0; j < 9; ++j) u[j] = pl[(c*9 + j)*66 + px];

        float xraw = x[((b*CFULL + CH + c)*HH + h)*WW + w0 + px];
        bool inside = (xraw >= -1.f) && (xraw <= 1.f);
        float xc = fminf(fmaxf(xraw, -1.f), 1.f);
        float in01 = (xc + 1.f) * 0.5f;

        // softmax over u[0..4] -> widths
        float m = u[0];
#pragma unroll
        for (int i = 1; i < 5; ++i) m = fmaxf(m, u[i]);
        float e[5], es = 0.f;
#pragma unroll
        for (int i = 0; i < 5; ++i) { e[i] = expf(u[i] - m); es += e[i]; }
        float wdt[5];
#pragma unroll
        for (int i = 0; i < 5; ++i) wdt[i] = 0.001f + (1.f - 0.001f*NB) * (e[i] / es);

        float eh[4];
#pragma unroll
        for (int i = 0; i < 4; ++i) eh[i] = expf(u[5 + i]);

        float first_w = 0.5f * wdt[0], last_w = 0.5f * wdt[4];
        float numer = 0.5f*first_w*eh[0] + 0.5f*last_w*eh[3]
                    + 0.5f*(eh[0]+eh[1])*wdt[1]
                    + 0.5f*(eh[1]+eh[2])*wdt[2]
                    + 0.5f*(eh[2]+eh[3])*wdt[3];
        float cst = numer / (1.f - 0.5f*first_w - 0.5f*last_w);

        float kn[6] = {cst, eh[0], eh[1], eh[2], eh[3], cst};
        float area = 0.f;
#pragma unroll
        for (int i = 0; i < 5; ++i) area += 0.5f*(kn[i]+kn[i+1])*wdt[i];
        float hts[6];
#pragma unroll
        for (int i = 0; i < 6; ++i) hts[i] = 0.001f + (1.f - 0.001f) * (kn[i] / area);

        float C[6]; C[0] = 0.f;
#pragma unroll
        for (int i = 0; i < 5; ++i) C[i+1] = C[i] + 0.5f*(hts[i]+hts[i+1])*wdt[i];
        C[5] = 1.f;
        float L[6]; L[0] = 0.f;
#pragma unroll
        for (int i = 0; i < 5; ++i) L[i+1] = L[i] + wdt[i];
        L[5] = 1.f;

        int idx = 0;
#pragma unroll
        for (int i = 1; i < 6; ++i) idx += (in01 >= L[i]) ? 1 : 0;
        idx = min(idx, 4);

        float loc = L[0], cdf = C[0], hl = hts[0], hr = hts[1], wb = wdt[0];
#pragma unroll
        for (int i = 1; i < 5; ++i) {
            if (i == idx) { loc = L[i]; cdf = C[i]; hl = hts[i]; hr = hts[i+1]; wb = wdt[i]; }
        }

        float alpha = (in01 - loc) / wb;
        float aa = 0.5f*(hr - hl)*wb;
        float bb = hl*wb;
        float o = fminf(fmaxf(aa*alpha*alpha + bb*alpha + cdf, 0.f), 1.f);
        float sl = logf(alpha*(hr - hl) + hl);
        float outv = o*2.f - 1.f;
        if (!inside) { outv = xraw; sl = 0.f; }
        out[((b*CFULL + CH + c)*HH + h)*WW + w0 + px] = outv;
        lad = sl;
    }

    // block-reduce lad, one atomic per block
#pragma unroll
    for (int off = 32; off > 0; off >>= 1) lad += __shfl_down(lad, off, 64);
    if ((tid & 63) == 0) red[tid >> 6] = lad;
    __syncthreads();
    if (tid == 0) {
        float s = 0.f;
#pragma unroll
        for (int i = 0; i < 8; ++i) s += red[i];
        atomicAdd(&obj[b], s);
    }
}

extern "C" void kernel_launch(void* const* d_in, const int* in_sizes, int n_in,
                              void* d_out, int out_size, void* d_ws, size_t ws_size,
                              hipStream_t stream) {
    const float* x   = (const float*)d_in[0];
    const float* obj = (const float*)d_in[1];
    const float* w1  = (const float*)d_in[2];
    const float* b1  = (const float*)d_in[3];
    const float* w2  = (const float*)d_in[4];
    const float* b2  = (const float*)d_in[5];
    const float* w3  = (const float*)d_in[6];
    const float* b3  = (const float*)d_in[7];

    float* out_t  = (float*)d_out;
    float* obj_o  = out_t + OUT_ELEMS;
    float* h2     = (float*)d_ws;          // B*128*128*128 floats = 268 MB

    k_init_obj<<<1, 64, 0, stream>>>(obj, obj_o);
    k_conv12<<<B*HH, 256, 0, stream>>>(x, w1, b1, w2, b2, h2);
    k_conv3_spline<<<dim3(2, HH, B), 512, 0, stream>>>(x, h2, w3, b3, out_t, obj_o);
}

// Round 2
// 1075.110 us; speedup vs baseline: 3.1980x; 3.1980x over previous
//
#include <hip/hip_runtime.h>
#include <hip/hip_bf16.h>
#include <math.h>

#define B 32
#define CFULL 12
#define CH 6
#define HH 128
#define WW 128
#define HID 128
#define CO3 54
#define NB 5
#define OUT_ELEMS (B*CFULL*HH*WW)
#define H2_BYTES (size_t)(B*HH*WW*HID*2)        // bf16 channels-last [b][h][w][ci]
#define WFRAG_ELEMS (9*4*4*64*8)                 // 73728 bf16 = 147456 B

typedef __bf16 bf16x8 __attribute__((ext_vector_type(8)));
typedef float f32x4 __attribute__((ext_vector_type(4)));

__device__ __forceinline__ ushort f2bf(float f) {
    uint b = __float_as_uint(f);
    uint r = (b + 0x7FFFu + ((b >> 16) & 1u)) >> 16;
    return (ushort)r;
}

union UBF { uint4 u; bf16x8 b; };

// ---------------- init objective ----------------
__global__ void k_init_obj(const float* __restrict__ obj_in, float* __restrict__ obj_out) {
    int i = threadIdx.x;
    if (i < B) obj_out[i] = obj_in[i];
}

// ---------------- weight prep: w3 [54][128][3][3] fp32 -> B-fragment order bf16 ----------------
// Wfrag index: (((t*4 + kb)*4 + nf)*64 + lane)*8 + j
// element value: B_tap[k=ci][n=co] = w3[co][ci][t] with co=nf*16+(lane&15), ci=kb*32+8*(lane>>4)+j
__global__ __launch_bounds__(256) void k_prep(const float* __restrict__ w3, ushort* __restrict__ Wfrag) {
    int idx = blockIdx.x * 256 + threadIdx.x;
    if (idx >= WFRAG_ELEMS) return;
    int j    = idx & 7;
    int lane = (idx >> 3) & 63;
    int nf   = (idx >> 9) & 3;
    int kb   = (idx >> 11) & 3;
    int t    = idx >> 13;
    int co = nf * 16 + (lane & 15);
    int ci = kb * 32 + 8 * (lane >> 4) + j;
    float v = (co < CO3) ? w3[(co * HID + ci) * 9 + t] : 0.f;
    Wfrag[idx] = f2bf(v);
}

// ---------------- conv1(3x3,6->128)+relu fused with conv2(1x1,128->128)+relu ----------------
// writes h2 as bf16 channels-last: h2[((b*HH+h)*WW+w)*HID + ci]
__global__ __launch_bounds__(256) void k_conv12(
    const float* __restrict__ x,
    const float* __restrict__ w1, const float* __restrict__ b1,
    const float* __restrict__ w2, const float* __restrict__ b2,
    ushort* __restrict__ h2)
{
    __shared__ float xs[CH][3][132];
    __shared__ float h1row[HID][HH];

    const int b = blockIdx.x >> 7;
    const int h = blockIdx.x & 127;
    const int tid = threadIdx.x;

    for (int i = tid; i < CH*3*130; i += 256) {
        int ci = i / 390; int rem = i - ci*390;
        int r = rem / 130; int xw = rem - r*130;
        int hh = h + r - 1, ww = xw - 1;
        float v = 0.f;
        if (hh >= 0 && hh < HH && ww >= 0 && ww < WW)
            v = x[((b*CFULL + ci)*HH + hh)*WW + ww];
        xs[ci][r][xw] = v;
    }
    __syncthreads();

    const int w  = tid & 127;
    const int cog = __builtin_amdgcn_readfirstlane(tid >> 7);   // 0..1

    float p[54];
#pragma unroll
    for (int ci = 0; ci < CH; ++ci)
#pragma unroll
        for (int r = 0; r < 3; ++r)
#pragma unroll
            for (int dx = 0; dx < 3; ++dx)
                p[(ci*3+r)*3+dx] = xs[ci][r][w + dx];

    for (int k = 0; k < 64; ++k) {
        int co = cog*64 + k;
        const float* wp = w1 + co*54;
        float acc = b1[co];
#pragma unroll
        for (int s = 0; s < 54; ++s) acc = fmaf(wp[s], p[s], acc);
        h1row[co][w] = fmaxf(acc, 0.f);
    }
    __syncthreads();

    const int pixbase = ((b*HH + h)*WW + w) * HID;
    for (int k0 = 0; k0 < 64; k0 += 8) {
        int cob = cog*64 + k0;
        float acc[8];
#pragma unroll
        for (int j = 0; j < 8; ++j) acc[j] = b2[cob + j];
        for (int ci = 0; ci < HID; ci += 4) {
            float x0 = h1row[ci  ][w];
            float x1 = h1row[ci+1][w];
            float x2 = h1row[ci+2][w];
            float x3 = h1row[ci+3][w];
#pragma unroll
            for (int j = 0; j < 8; ++j) {
                const float* wr = w2 + (cob + j)*HID + ci;
                acc[j] = fmaf(wr[0], x0, acc[j]);
                acc[j] = fmaf(wr[1], x1, acc[j]);
                acc[j] = fmaf(wr[2], x2, acc[j]);
                acc[j] = fmaf(wr[3], x3, acc[j]);
            }
        }
        uint4 v;
        ushort u0 = f2bf(fmaxf(acc[0],0.f)), u1 = f2bf(fmaxf(acc[1],0.f));
        ushort u2 = f2bf(fmaxf(acc[2],0.f)), u3 = f2bf(fmaxf(acc[3],0.f));
        ushort u4 = f2bf(fmaxf(acc[4],0.f)), u5 = f2bf(fmaxf(acc[5],0.f));
        ushort u6 = f2bf(fmaxf(acc[6],0.f)), u7 = f2bf(fmaxf(acc[7],0.f));
        v.x = (uint)u0 | ((uint)u1 << 16);
        v.y = (uint)u2 | ((uint)u3 << 16);
        v.z = (uint)u4 | ((uint)u5 << 16);
        v.w = (uint)u6 | ((uint)u7 << 16);
        *(uint4*)&h2[pixbase + cob] = v;
    }
}

// ---------------- conv3 (MFMA bf16) + spline + identity copy + objective ----------------
// block: (wtile 0..1, h, b); 256 threads = 4 waves; wave wv = M-frag (16 px), all 4 N-frags (64 co)
__global__ __launch_bounds__(256) void k_conv3_spline(
    const float* __restrict__ x,
    const ushort* __restrict__ h2,
    const ushort* __restrict__ Wfrag, const float* __restrict__ b3,
    float* __restrict__ out, float* __restrict__ obj)
{
    __shared__ ushort xs[3*66*128];      // [r][wl][ci] bf16, XOR-swizzled within each 256B ci-row
    __shared__ float pl[64*68];          // params [co][px] (stride 68)
    __shared__ float red[4];

    const int w0 = blockIdx.x * 64;
    const int h  = blockIdx.y;
    const int b  = blockIdx.z;
    const int tid = threadIdx.x;

    char* xsb = (char*)xs;

    // ---- stage h2 tile: 3 rows x 66 w x 128 ci, 16B chunks ----
    for (int i = tid; i < 3*66*16; i += 256) {
        int r = i / 1056; int rem = i - r*1056;
        int wl = rem >> 4; int c16 = rem & 15;
        int hh = h + r - 1, ww = w0 + wl - 1;
        uint4 v = {0,0,0,0};
        if (hh >= 0 && hh < HH && ww >= 0 && ww < WW)
            v = *(const uint4*)&h2[(size_t)((b*HH + hh)*WW + ww) * HID + c16*8];
        int swz = (wl & 7) << 4;
        *(uint4*)(xsb + (r*66 + wl)*256 + ((c16*16) ^ swz)) = v;
    }
    __syncthreads();

    // ---- MFMA main loop ----
    const int lane = tid & 63;
    const int wv   = tid >> 6;          // 0..3 = M-frag
    const int kg   = lane >> 4;         // 0..3
    const int lr   = lane & 15;

    f32x4 acc0 = {0.f,0.f,0.f,0.f};
    f32x4 acc1 = acc0, acc2 = acc0, acc3 = acc0;
    const char* wbase = (const char*)Wfrag;

#pragma unroll 1
    for (int r = 0; r < 3; ++r) {
#pragma unroll 1
        for (int dx = 0; dx < 3; ++dx) {
            const int wl = wv*16 + lr + dx;
            const int swz = (wl & 7) << 4;
            const int rowbase = (r*66 + wl) << 8;
            const int t = r*3 + dx;
#pragma unroll
            for (int kb = 0; kb < 4; ++kb) {
                UBF a; a.u = *(const uint4*)(xsb + rowbase + (((kb<<6) + (kg<<4)) ^ swz));
                const char* wp = wbase + (((t<<2) + kb) << 12) + (lane << 4);
                UBF b0; b0.u = *(const uint4*)(wp);
                UBF b1; b1.u = *(const uint4*)(wp + 1024);
                UBF b2; b2.u = *(const uint4*)(wp + 2048);
                UBF b3f; b3f.u = *(const uint4*)(wp + 3072);
                acc0 = __builtin_amdgcn_mfma_f32_16x16x32_bf16(a.b, b0.b,  acc0, 0, 0, 0);
                acc1 = __builtin_amdgcn_mfma_f32_16x16x32_bf16(a.b, b1.b,  acc1, 0, 0, 0);
                acc2 = __builtin_amdgcn_mfma_f32_16x16x32_bf16(a.b, b2.b,  acc2, 0, 0, 0);
                acc3 = __builtin_amdgcn_mfma_f32_16x16x32_bf16(a.b, b3f.b, acc3, 0, 0, 0);
            }
        }
    }

    // ---- write params to LDS: C/D layout col=lane&15 (co), row=(lane>>4)*4+reg (px) ----
    {
        const int px0 = (wv << 4) + (kg << 2);
        *(f32x4*)&pl[(0*16 + lr)*68 + px0] = acc0;
        *(f32x4*)&pl[(1*16 + lr)*68 + px0] = acc1;
        *(f32x4*)&pl[(2*16 + lr)*68 + px0] = acc2;
        *(f32x4*)&pl[(3*16 + lr)*68 + px0] = acc3;
    }
    __syncthreads();

    // ---- spline + identity copy ----
    float lad = 0.f;
    for (int i = tid; i < 384; i += 256) {
        const int c  = __builtin_amdgcn_readfirstlane(i >> 6);
        const int px = i & 63;
        const int wg = w0 + px;

        out[((b*CFULL + c)*HH + h)*WW + wg] = x[((b*CFULL + c)*HH + h)*WW + wg];

        float u[9];
#pragma unroll
        for (int j = 0; j < 9; ++j) u[j] = pl[(c*9 + j)*68 + px] + b3[c*9 + j];

        float xraw = x[((b*CFULL + CH + c)*HH + h)*WW + wg];
        bool inside = (xraw >= -1.f) && (xraw <= 1.f);
        float xc = fminf(fmaxf(xraw, -1.f), 1.f);
        float in01 = (xc + 1.f) * 0.5f;

        float m = u[0];
#pragma unroll
        for (int i2 = 1; i2 < 5; ++i2) m = fmaxf(m, u[i2]);
        float e[5], es = 0.f;
#pragma unroll
        for (int i2 = 0; i2 < 5; ++i2) { e[i2] = expf(u[i2] - m); es += e[i2]; }
        float wdt[5];
#pragma unroll
        for (int i2 = 0; i2 < 5; ++i2) wdt[i2] = 0.001f + (1.f - 0.001f*NB) * (e[i2] / es);

        float eh[4];
#pragma unroll
        for (int i2 = 0; i2 < 4; ++i2) eh[i2] = expf(u[5 + i2]);

        float first_w = 0.5f * wdt[0], last_w = 0.5f * wdt[4];
        float numer = 0.5f*first_w*eh[0] + 0.5f*last_w*eh[3]
                    + 0.5f*(eh[0]+eh[1])*wdt[1]
                    + 0.5f*(eh[1]+eh[2])*wdt[2]
                    + 0.5f*(eh[2]+eh[3])*wdt[3];
        float cst = numer / (1.f - 0.5f*first_w - 0.5f*last_w);

        float kn[6] = {cst, eh[0], eh[1], eh[2], eh[3], cst};
        float area = 0.f;
#pragma unroll
        for (int i2 = 0; i2 < 5; ++i2) area += 0.5f*(kn[i2]+kn[i2+1])*wdt[i2];
        float hts[6];
#pragma unroll
        for (int i2 = 0; i2 < 6; ++i2) hts[i2] = 0.001f + (1.f - 0.001f) * (kn[i2] / area);

        float C[6]; C[0] = 0.f;
#pragma unroll
        for (int i2 = 0; i2 < 5; ++i2) C[i2+1] = C[i2] + 0.5f*(hts[i2]+hts[i2+1])*wdt[i2];
        C[5] = 1.f;
        float L[6]; L[0] = 0.f;
#pragma unroll
        for (int i2 = 0; i2 < 5; ++i2) L[i2+1] = L[i2] + wdt[i2];
        L[5] = 1.f;

        int idx = 0;
#pragma unroll
        for (int i2 = 1; i2 < 6; ++i2) idx += (in01 >= L[i2]) ? 1 : 0;
        idx = min(idx, 4);

        float loc = L[0], cdf = C[0], hl = hts[0], hr = hts[1], wb2 = wdt[0];
#pragma unroll
        for (int i2 = 1; i2 < 5; ++i2) {
            if (i2 == idx) { loc = L[i2]; cdf = C[i2]; hl = hts[i2]; hr = hts[i2+1]; wb2 = wdt[i2]; }
        }

        float alpha = (in01 - loc) / wb2;
        float aa = 0.5f*(hr - hl)*wb2;
        float bb = hl*wb2;
        float o = fminf(fmaxf(aa*alpha*alpha + bb*alpha + cdf, 0.f), 1.f);
        float sl = logf(alpha*(hr - hl) + hl);
        float outv = o*2.f - 1.f;
        if (!inside) { outv = xraw; sl = 0.f; }
        out[((b*CFULL + CH + c)*HH + h)*WW + wg] = outv;
        lad += sl;
    }

#pragma unroll
    for (int off = 32; off > 0; off >>= 1) lad += __shfl_down(lad, off, 64);
    if ((tid & 63) == 0) red[tid >> 6] = lad;
    __syncthreads();
    if (tid == 0) {
        float s = red[0] + red[1] + red[2] + red[3];
        atomicAdd(&obj[b], s);
    }
}

extern "C" void kernel_launch(void* const* d_in, const int* in_sizes, int n_in,
                              void* d_out, int out_size, void* d_ws, size_t ws_size,
                              hipStream_t stream) {
    const float* x   = (const float*)d_in[0];
    const float* obj = (const float*)d_in[1];
    const float* w1  = (const float*)d_in[2];
    const float* b1  = (const float*)d_in[3];
    const float* w2  = (const float*)d_in[4];
    const float* b2  = (const float*)d_in[5];
    const float* w3  = (const float*)d_in[6];
    const float* b3  = (const float*)d_in[7];

    float* out_t = (float*)d_out;
    float* obj_o = out_t + OUT_ELEMS;
    ushort* h2    = (ushort*)d_ws;
    ushort* Wfrag = (ushort*)((char*)d_ws + H2_BYTES);

    k_init_obj<<<1, 64, 0, stream>>>(obj, obj_o);
    k_prep<<<(WFRAG_ELEMS + 255)/256, 256, 0, stream>>>(w3, Wfrag);
    k_conv12<<<B*HH, 256, 0, stream>>>(x, w1, b1, w2, b2, h2);
    k_conv3_spline<<<dim3(2, HH, B), 256, 0, stream>>>(x, h2, Wfrag, b3, out_t, obj_o);
}

// Round 3
// 558.228 us; speedup vs baseline: 6.1592x; 1.9259x over previous
//
#include <hip/hip_runtime.h>
#include <hip/hip_bf16.h>
#include <math.h>

#define B 32
#define CFULL 12
#define CH 6
#define HH 128
#define WW 128
#define HID 128
#define CO3 54
#define NB 5
#define OUT_ELEMS (B*CFULL*HH*WW)
#define H2_BYTES (size_t)(B*HH*WW*HID*2)        // bf16 channels-last [b][h][w][ci]
#define WFRAG_ELEMS (9*4*4*64*8)                 // w3 frags: 73728 bf16
#define W1F_ELEMS (2*8*64*8)                     // 8192
#define W2F_ELEMS (4*8*64*8)                     // 16384

typedef __bf16 bf16x8 __attribute__((ext_vector_type(8)));
typedef float f32x4 __attribute__((ext_vector_type(4)));

__device__ __forceinline__ ushort f2bf(float f) {
    uint b = __float_as_uint(f);
    uint r = (b + 0x7FFFu + ((b >> 16) & 1u)) >> 16;
    return (ushort)r;
}
__device__ __forceinline__ uint pack2(float a, float b) {
    return (uint)f2bf(a) | ((uint)f2bf(b) << 16);
}

union UBF { uint4 u; bf16x8 b; };

// ---------------- init objective ----------------
__global__ void k_init_obj(const float* __restrict__ obj_in, float* __restrict__ obj_out) {
    int i = threadIdx.x;
    if (i < B) obj_out[i] = obj_in[i];
}

// ---------------- weight prep: w3 -> B-fragment order bf16 ----------------
__global__ __launch_bounds__(256) void k_prep(const float* __restrict__ w3, ushort* __restrict__ Wfrag) {
    int idx = blockIdx.x * 256 + threadIdx.x;
    if (idx >= WFRAG_ELEMS) return;
    int j    = idx & 7;
    int lane = (idx >> 3) & 63;
    int nf   = (idx >> 9) & 3;
    int kb   = (idx >> 11) & 3;
    int t    = idx >> 13;
    int co = nf * 16 + (lane & 15);
    int ci = kb * 32 + 8 * (lane >> 4) + j;
    float v = (co < CO3) ? w3[(co * HID + ci) * 9 + t] : 0.f;
    Wfrag[idx] = f2bf(v);
}

// ---------------- weight prep: w1 (K=54 pad 64), w2 (K=128) -> B-frag bf16 ----------------
__global__ __launch_bounds__(256) void k_prep12(const float* __restrict__ w1, const float* __restrict__ w2,
                                                ushort* __restrict__ W1f, ushort* __restrict__ W2f) {
    int idx = blockIdx.x * 256 + threadIdx.x;
    if (idx < W1F_ELEMS) {
        int j = idx & 7, lane = (idx >> 3) & 63, nf = (idx >> 9) & 7, ks = idx >> 12;
        int co = nf * 16 + (lane & 15);
        int k  = ks * 32 + (lane >> 4) * 8 + j;
        W1f[idx] = f2bf(k < 54 ? w1[co * 54 + k] : 0.f);
    } else {
        int i2 = idx - W1F_ELEMS;
        if (i2 < W2F_ELEMS) {
            int j = i2 & 7, lane = (i2 >> 3) & 63, nf = (i2 >> 9) & 7, ks = (i2 >> 12) & 3;
            int co = nf * 16 + (lane & 15);
            int ci = ks * 32 + (lane >> 4) * 8 + j;
            W2f[i2] = f2bf(w2[co * 128 + ci]);
        }
    }
}

// ---------------- conv1+conv2 via MFMA, writes h2 bf16 channels-last ----------------
__global__ __launch_bounds__(256) void k_conv12(
    const float* __restrict__ x,
    const ushort* __restrict__ W1f, const float* __restrict__ b1,
    const ushort* __restrict__ W2f, const float* __restrict__ b2,
    ushort* __restrict__ h2)
{
    __shared__ char buf1[32768];   // xs(9504B) + A_lds(16KB); later h2 staging (32KB)
    __shared__ char buf2[32768];   // h1 [128px][128co] bf16 swizzled

    float* xs = (float*)buf1;                 // [6][3][132] fp32
    char* Albase = buf1 + 9728;               // A [128px][64k] bf16 swizzled
    char* h1 = buf2;
    char* h2st = buf1;

    const int b = blockIdx.x >> 7;
    const int h = blockIdx.x & 127;
    const int tid = threadIdx.x;
    const int lane = tid & 63;
    const int wv = tid >> 6;        // 0..3
    const int lr = lane & 15;
    const int kg = lane >> 4;       // 0..3

    // ---- stage x rows: 6ch x 3r x 130w ----
    for (int i = tid; i < 6*3*130; i += 256) {
        int ci = i / 390; int rem = i - ci*390;
        int r = rem / 130; int xw = rem - r*130;
        int hh = h + r - 1, ww = xw - 1;
        float v = 0.f;
        if (hh >= 0 && hh < HH && ww >= 0 && ww < WW)
            v = x[((b*CFULL + ci)*HH + hh)*WW + ww];
        xs[(ci*3 + r)*132 + xw] = v;
    }
    __syncthreads();

    // ---- build im2col A: [128px][64k], k = ci*9 + r*3 + dx (54 used) ----
    for (int it = 0; it < 4; ++it) {
        int item = (it << 8) + tid;          // 1024 items
        int px = item & 127;
        int g  = item >> 7;                  // 0..7
        uint pk[4];
#pragma unroll
        for (int jj = 0; jj < 4; ++jj) {
            int k0 = g*8 + jj*2;
            int k1 = k0 + 1;
            float v0 = 0.f, v1 = 0.f;
            if (k0 < 54) { int ci = k0/9; int rem = k0 - ci*9; int r = rem/3; int dx = rem - r*3;
                           v0 = xs[(ci*3 + r)*132 + px + dx]; }
            if (k1 < 54) { int ci = k1/9; int rem = k1 - ci*9; int r = rem/3; int dx = rem - r*3;
                           v1 = xs[(ci*3 + r)*132 + px + dx]; }
            pk[jj] = pack2(v0, v1);
        }
        uint4 q; q.x = pk[0]; q.y = pk[1]; q.z = pk[2]; q.w = pk[3];
        *(uint4*)(Albase + px*128 + ((g << 4) ^ (((px >> 1) & 7) << 4))) = q;
    }
    __syncthreads();

    // ---- conv1 MFMA: M=32px/wave, N=128, K=64 ----
    f32x4 acc[2][8];
#pragma unroll
    for (int mm = 0; mm < 2; ++mm)
#pragma unroll
        for (int nf = 0; nf < 8; ++nf) acc[mm][nf] = (f32x4){0.f,0.f,0.f,0.f};

    const int px0 = wv*32 + lr;
    const int px1 = px0 + 16;
#pragma unroll
    for (int ks = 0; ks < 2; ++ks) {
        UBF a0, a1;
        a0.u = *(const uint4*)(Albase + px0*128 + ((ks*64 + kg*16) ^ (((px0 >> 1) & 7) << 4)));
        a1.u = *(const uint4*)(Albase + px1*128 + ((ks*64 + kg*16) ^ (((px1 >> 1) & 7) << 4)));
        const char* wp = (const char*)W1f + ks*8192 + lane*16;
#pragma unroll
        for (int nf = 0; nf < 8; ++nf) {
            UBF bf; bf.u = *(const uint4*)(wp + nf*1024);
            acc[0][nf] = __builtin_amdgcn_mfma_f32_16x16x32_bf16(a0.b, bf.b, acc[0][nf], 0, 0, 0);
            acc[1][nf] = __builtin_amdgcn_mfma_f32_16x16x32_bf16(a1.b, bf.b, acc[1][nf], 0, 0, 0);
        }
    }

    // ---- h1 = relu(conv1+b1) -> LDS [px][co] bf16 swizzled ----
    float b1v[8];
#pragma unroll
    for (int nf = 0; nf < 8; ++nf) b1v[nf] = b1[nf*16 + lr];
#pragma unroll
    for (int mm = 0; mm < 2; ++mm)
#pragma unroll
        for (int nf = 0; nf < 8; ++nf) {
            int co2 = (nf*16 + lr) * 2;
#pragma unroll
            for (int rg = 0; rg < 4; ++rg) {
                int px = wv*32 + mm*16 + kg*4 + rg;
                float v = fmaxf(acc[mm][nf][rg] + b1v[nf], 0.f);
                *(ushort*)(h1 + px*256 + (co2 ^ (((px >> 1) & 7) << 4))) = f2bf(v);
            }
        }
    __syncthreads();

    // ---- conv2 MFMA: K=128 ----
#pragma unroll
    for (int mm = 0; mm < 2; ++mm)
#pragma unroll
        for (int nf = 0; nf < 8; ++nf) acc[mm][nf] = (f32x4){0.f,0.f,0.f,0.f};
#pragma unroll
    for (int ks = 0; ks < 4; ++ks) {
        UBF a0, a1;
        a0.u = *(const uint4*)(h1 + px0*256 + ((ks*64 + kg*16) ^ (((px0 >> 1) & 7) << 4)));
        a1.u = *(const uint4*)(h1 + px1*256 + ((ks*64 + kg*16) ^ (((px1 >> 1) & 7) << 4)));
        const char* wp = (const char*)W2f + ks*8192 + lane*16;
#pragma unroll
        for (int nf = 0; nf < 8; ++nf) {
            UBF bf; bf.u = *(const uint4*)(wp + nf*1024);
            acc[0][nf] = __builtin_amdgcn_mfma_f32_16x16x32_bf16(a0.b, bf.b, acc[0][nf], 0, 0, 0);
            acc[1][nf] = __builtin_amdgcn_mfma_f32_16x16x32_bf16(a1.b, bf.b, acc[1][nf], 0, 0, 0);
        }
    }

    __syncthreads();   // all A_lds reads done (buf1 about to be reused as h2st)

    // ---- h2 = relu(conv2+b2) -> staging LDS (swizzled) ----
    float b2v[8];
#pragma unroll
    for (int nf = 0; nf < 8; ++nf) b2v[nf] = b2[nf*16 + lr];
#pragma unroll
    for (int mm = 0; mm < 2; ++mm)
#pragma unroll
        for (int nf = 0; nf < 8; ++nf) {
            int co2 = (nf*16 + lr) * 2;
#pragma unroll
            for (int rg = 0; rg < 4; ++rg) {
                int px = wv*32 + mm*16 + kg*4 + rg;
                float v = fmaxf(acc[mm][nf][rg] + b2v[nf], 0.f);
                *(ushort*)(h2st + px*256 + (co2 ^ (((px >> 1) & 7) << 4))) = f2bf(v);
            }
        }
    __syncthreads();

    // ---- coalesced copy: 32KB tile is contiguous in h2 ----
    const size_t outbase = (size_t)((b*HH + h)*WW) * HID;
    for (int c = tid; c < 2048; c += 256) {
        int px = c >> 4; int cb = (c & 15) << 4;
        uint4 v = *(const uint4*)(h2st + px*256 + (cb ^ (((px >> 1) & 7) << 4)));
        *(uint4*)&h2[outbase + (size_t)c*8] = v;
    }
}

// ---------------- conv3 (MFMA bf16) + spline + identity copy + objective ----------------
__global__ __launch_bounds__(256) void k_conv3_spline(
    const float* __restrict__ x,
    const ushort* __restrict__ h2,
    const ushort* __restrict__ Wfrag, const float* __restrict__ b3,
    float* __restrict__ out, float* __restrict__ obj)
{
    __shared__ ushort xs[3*66*128];
    __shared__ float pl[64*68];
    __shared__ float red[4];

    const int w0 = blockIdx.x * 64;
    const int h  = blockIdx.y;
    const int b  = blockIdx.z;
    const int tid = threadIdx.x;

    char* xsb = (char*)xs;

    for (int i = tid; i < 3*66*16; i += 256) {
        int r = i / 1056; int rem = i - r*1056;
        int wl = rem >> 4; int c16 = rem & 15;
        int hh = h + r - 1, ww = w0 + wl - 1;
        uint4 v = {0,0,0,0};
        if (hh >= 0 && hh < HH && ww >= 0 && ww < WW)
            v = *(const uint4*)&h2[(size_t)((b*HH + hh)*WW + ww) * HID + c16*8];
        int swz = (wl & 7) << 4;
        *(uint4*)(xsb + (r*66 + wl)*256 + ((c16*16) ^ swz)) = v;
    }
    __syncthreads();

    const int lane = tid & 63;
    const int wv   = tid >> 6;
    const int kg   = lane >> 4;
    const int lr   = lane & 15;

    f32x4 acc0 = {0.f,0.f,0.f,0.f};
    f32x4 acc1 = acc0, acc2 = acc0, acc3 = acc0;
    const char* wbase = (const char*)Wfrag;

#pragma unroll 1
    for (int r = 0; r < 3; ++r) {
#pragma unroll 1
        for (int dx = 0; dx < 3; ++dx) {
            const int wl = wv*16 + lr + dx;
            const int swz = (wl & 7) << 4;
            const int rowbase = (r*66 + wl) << 8;
            const int t = r*3 + dx;
#pragma unroll
            for (int kb = 0; kb < 4; ++kb) {
                UBF a; a.u = *(const uint4*)(xsb + rowbase + (((kb<<6) + (kg<<4)) ^ swz));
                const char* wp = wbase + (((t<<2) + kb) << 12) + (lane << 4);
                UBF b0; b0.u = *(const uint4*)(wp);
                UBF b1; b1.u = *(const uint4*)(wp + 1024);
                UBF b2; b2.u = *(const uint4*)(wp + 2048);
                UBF b3f; b3f.u = *(const uint4*)(wp + 3072);
                acc0 = __builtin_amdgcn_mfma_f32_16x16x32_bf16(a.b, b0.b,  acc0, 0, 0, 0);
                acc1 = __builtin_amdgcn_mfma_f32_16x16x32_bf16(a.b, b1.b,  acc1, 0, 0, 0);
                acc2 = __builtin_amdgcn_mfma_f32_16x16x32_bf16(a.b, b2.b,  acc2, 0, 0, 0);
                acc3 = __builtin_amdgcn_mfma_f32_16x16x32_bf16(a.b, b3f.b, acc3, 0, 0, 0);
            }
        }
    }

    {
        const int px0 = (wv << 4) + (kg << 2);
        *(f32x4*)&pl[(0*16 + lr)*68 + px0] = acc0;
        *(f32x4*)&pl[(1*16 + lr)*68 + px0] = acc1;
        *(f32x4*)&pl[(2*16 + lr)*68 + px0] = acc2;
        *(f32x4*)&pl[(3*16 + lr)*68 + px0] = acc3;
    }
    __syncthreads();

    float lad = 0.f;
    for (int i = tid; i < 384; i += 256) {
        const int c  = __builtin_amdgcn_readfirstlane(i >> 6);
        const int px = i & 63;
        const int wg = w0 + px;

        out[((b*CFULL + c)*HH + h)*WW + wg] = x[((b*CFULL + c)*HH + h)*WW + wg];

        float u[9];
#pragma unroll
        for (int j = 0; j < 9; ++j) u[j] = pl[(c*9 + j)*68 + px] + b3[c*9 + j];

        float xraw = x[((b*CFULL + CH + c)*HH + h)*WW + wg];
        bool inside = (xraw >= -1.f) && (xraw <= 1.f);
        float xc = fminf(fmaxf(xraw, -1.f), 1.f);
        float in01 = (xc + 1.f) * 0.5f;

        float m = u[0];
#pragma unroll
        for (int i2 = 1; i2 < 5; ++i2) m = fmaxf(m, u[i2]);
        float e[5], es = 0.f;
#pragma unroll
        for (int i2 = 0; i2 < 5; ++i2) { e[i2] = expf(u[i2] - m); es += e[i2]; }
        float wdt[5];
#pragma unroll
        for (int i2 = 0; i2 < 5; ++i2) wdt[i2] = 0.001f + (1.f - 0.001f*NB) * (e[i2] / es);

        float eh[4];
#pragma unroll
        for (int i2 = 0; i2 < 4; ++i2) eh[i2] = expf(u[5 + i2]);

        float first_w = 0.5f * wdt[0], last_w = 0.5f * wdt[4];
        float numer = 0.5f*first_w*eh[0] + 0.5f*last_w*eh[3]
                    + 0.5f*(eh[0]+eh[1])*wdt[1]
                    + 0.5f*(eh[1]+eh[2])*wdt[2]
                    + 0.5f*(eh[2]+eh[3])*wdt[3];
        float cst = numer / (1.f - 0.5f*first_w - 0.5f*last_w);

        float kn[6] = {cst, eh[0], eh[1], eh[2], eh[3], cst};
        float area = 0.f;
#pragma unroll
        for (int i2 = 0; i2 < 5; ++i2) area += 0.5f*(kn[i2]+kn[i2+1])*wdt[i2];
        float hts[6];
#pragma unroll
        for (int i2 = 0; i2 < 6; ++i2) hts[i2] = 0.001f + (1.f - 0.001f) * (kn[i2] / area);

        float C[6]; C[0] = 0.f;
#pragma unroll
        for (int i2 = 0; i2 < 5; ++i2) C[i2+1] = C[i2] + 0.5f*(hts[i2]+hts[i2+1])*wdt[i2];
        C[5] = 1.f;
        float L[6]; L[0] = 0.f;
#pragma unroll
        for (int i2 = 0; i2 < 5; ++i2) L[i2+1] = L[i2] + wdt[i2];
        L[5] = 1.f;

        int idx = 0;
#pragma unroll
        for (int i2 = 1; i2 < 6; ++i2) idx += (in01 >= L[i2]) ? 1 : 0;
        idx = min(idx, 4);

        float loc = L[0], cdf = C[0], hl = hts[0], hr = hts[1], wb2 = wdt[0];
#pragma unroll
        for (int i2 = 1; i2 < 5; ++i2) {
            if (i2 == idx) { loc = L[i2]; cdf = C[i2]; hl = hts[i2]; hr = hts[i2+1]; wb2 = wdt[i2]; }
        }

        float alpha = (in01 - loc) / wb2;
        float aa = 0.5f*(hr - hl)*wb2;
        float bb = hl*wb2;
        float o = fminf(fmaxf(aa*alpha*alpha + bb*alpha + cdf, 0.f), 1.f);
        float sl = logf(alpha*(hr - hl) + hl);
        float outv = o*2.f - 1.f;
        if (!inside) { outv = xraw; sl = 0.f; }
        out[((b*CFULL + CH + c)*HH + h)*WW + wg] = outv;
        lad += sl;
    }

#pragma unroll
    for (int off = 32; off > 0; off >>= 1) lad += __shfl_down(lad, off, 64);
    if ((tid & 63) == 0) red[tid >> 6] = lad;
    __syncthreads();
    if (tid == 0) {
        float s = red[0] + red[1] + red[2] + red[3];
        atomicAdd(&obj[b], s);
    }
}

extern "C" void kernel_launch(void* const* d_in, const int* in_sizes, int n_in,
                              void* d_out, int out_size, void* d_ws, size_t ws_size,
                              hipStream_t stream) {
    const float* x   = (const float*)d_in[0];
    const float* obj = (const float*)d_in[1];
    const float* w1  = (const float*)d_in[2];
    const float* b1  = (const float*)d_in[3];
    const float* w2  = (const float*)d_in[4];
    const float* b2  = (const float*)d_in[5];
    const float* w3  = (const float*)d_in[6];
    const float* b3  = (const float*)d_in[7];

    float* out_t = (float*)d_out;
    float* obj_o = out_t + OUT_ELEMS;
    ushort* h2  = (ushort*)d_ws;
    ushort* W3f = (ushort*)((char*)d_ws + H2_BYTES);
    ushort* W1f = (ushort*)((char*)d_ws + H2_BYTES + 147456);
    ushort* W2f = (ushort*)((char*)d_ws + H2_BYTES + 147456 + 16384);

    k_init_obj<<<1, 64, 0, stream>>>(obj, obj_o);
    k_prep<<<(WFRAG_ELEMS + 255)/256, 256, 0, stream>>>(w3, W3f);
    k_prep12<<<(W1F_ELEMS + W2F_ELEMS + 255)/256, 256, 0, stream>>>(w1, w2, W1f, W2f);
    k_conv12<<<B*HH, 256, 0, stream>>>(x, W1f, b1, W2f, b2, h2);
    k_conv3_spline<<<dim3(2, HH, B), 256, 0, stream>>>(x, h2, W3f, b3, out_t, obj_o);
}

// Round 4
// 406.742 us; speedup vs baseline: 8.4531x; 1.3724x over previous
//
#include <hip/hip_runtime.h>
#include <hip/hip_bf16.h>
#include <math.h>

#define B 32
#define CFULL 12
#define CH 6
#define HH 128
#define WW 128
#define HID 128
#define CO3 54
#define NB 5
#define OUT_ELEMS (B*CFULL*HH*WW)
#define H2_BYTES (size_t)(B*HH*WW*HID*2)        // bf16 channels-last [b][h][w][ci]
#define WFRAG_ELEMS (9*4*4*64*8)                 // w3 frags: 73728 bf16
#define W1F_ELEMS (2*8*64*8)                     // 8192
#define W2F_ELEMS (4*8*64*8)                     // 16384

typedef __bf16 bf16x8 __attribute__((ext_vector_type(8)));
typedef float f32x4 __attribute__((ext_vector_type(4)));

__device__ __forceinline__ ushort f2bf(float f) {
    uint b = __float_as_uint(f);
    uint r = (b + 0x7FFFu + ((b >> 16) & 1u)) >> 16;
    return (ushort)r;
}
__device__ __forceinline__ uint pack2(float a, float b) {
    return (uint)f2bf(a) | ((uint)f2bf(b) << 16);
}

union UBF { uint4 u; bf16x8 b; };

// ---------------- init objective ----------------
__global__ void k_init_obj(const float* __restrict__ obj_in, float* __restrict__ obj_out) {
    int i = threadIdx.x;
    if (i < B) obj_out[i] = obj_in[i];
}

// ---------------- weight prep: w3 -> B-fragment order bf16 ----------------
__global__ __launch_bounds__(256) void k_prep(const float* __restrict__ w3, ushort* __restrict__ Wfrag) {
    int idx = blockIdx.x * 256 + threadIdx.x;
    if (idx >= WFRAG_ELEMS) return;
    int j    = idx & 7;
    int lane = (idx >> 3) & 63;
    int nf   = (idx >> 9) & 3;
    int kb   = (idx >> 11) & 3;
    int t    = idx >> 13;
    int co = nf * 16 + (lane & 15);
    int ci = kb * 32 + 8 * (lane >> 4) + j;
    float v = (co < CO3) ? w3[(co * HID + ci) * 9 + t] : 0.f;
    Wfrag[idx] = f2bf(v);
}

// ---------------- weight prep: w1 (K=54 pad 64), w2 (K=128) -> B-frag bf16 ----------------
__global__ __launch_bounds__(256) void k_prep12(const float* __restrict__ w1, const float* __restrict__ w2,
                                                ushort* __restrict__ W1f, ushort* __restrict__ W2f) {
    int idx = blockIdx.x * 256 + threadIdx.x;
    if (idx < W1F_ELEMS) {
        int j = idx & 7, lane = (idx >> 3) & 63, nf = (idx >> 9) & 7, ks = idx >> 12;
        int co = nf * 16 + (lane & 15);
        int k  = ks * 32 + (lane >> 4) * 8 + j;
        W1f[idx] = f2bf(k < 54 ? w1[co * 54 + k] : 0.f);
    } else {
        int i2 = idx - W1F_ELEMS;
        if (i2 < W2F_ELEMS) {
            int j = i2 & 7, lane = (i2 >> 3) & 63, nf = (i2 >> 9) & 7, ks = (i2 >> 12) & 3;
            int co = nf * 16 + (lane & 15);
            int ci = ks * 32 + (lane >> 4) * 8 + j;
            W2f[i2] = f2bf(w2[co * 128 + ci]);
        }
    }
}

// ---------------- conv1+conv2 via MFMA, writes h2 bf16 channels-last ----------------
__global__ __launch_bounds__(256) void k_conv12(
    const float* __restrict__ x,
    const ushort* __restrict__ W1f, const float* __restrict__ b1,
    const ushort* __restrict__ W2f, const float* __restrict__ b2,
    ushort* __restrict__ h2)
{
    __shared__ char buf1[32768];   // xs(9504B) + A_lds(16KB); later h2 staging (32KB)
    __shared__ char buf2[32768];   // h1 [128px][128co] bf16 swizzled

    float* xs = (float*)buf1;                 // [6][3][132] fp32
    char* Albase = buf1 + 9728;               // A [128px][64k] bf16 swizzled
    char* h1 = buf2;
    char* h2st = buf1;

    const int b = blockIdx.x >> 7;
    const int h = blockIdx.x & 127;
    const int tid = threadIdx.x;
    const int lane = tid & 63;
    const int wv = tid >> 6;        // 0..3
    const int lr = lane & 15;
    const int kg = lane >> 4;       // 0..3

    // ---- stage x rows: 6ch x 3r x 130w ----
    for (int i = tid; i < 6*3*130; i += 256) {
        int ci = i / 390; int rem = i - ci*390;
        int r = rem / 130; int xw = rem - r*130;
        int hh = h + r - 1, ww = xw - 1;
        float v = 0.f;
        if (hh >= 0 && hh < HH && ww >= 0 && ww < WW)
            v = x[((b*CFULL + ci)*HH + hh)*WW + ww];
        xs[(ci*3 + r)*132 + xw] = v;
    }
    __syncthreads();

    // ---- build im2col A: [128px][64k], k = ci*9 + r*3 + dx (54 used) ----
    for (int it = 0; it < 4; ++it) {
        int item = (it << 8) + tid;          // 1024 items
        int px = item & 127;
        int g  = item >> 7;                  // 0..7
        uint pk[4];
#pragma unroll
        for (int jj = 0; jj < 4; ++jj) {
            int k0 = g*8 + jj*2;
            int k1 = k0 + 1;
            float v0 = 0.f, v1 = 0.f;
            if (k0 < 54) { int ci = k0/9; int rem = k0 - ci*9; int r = rem/3; int dx = rem - r*3;
                           v0 = xs[(ci*3 + r)*132 + px + dx]; }
            if (k1 < 54) { int ci = k1/9; int rem = k1 - ci*9; int r = rem/3; int dx = rem - r*3;
                           v1 = xs[(ci*3 + r)*132 + px + dx]; }
            pk[jj] = pack2(v0, v1);
        }
        uint4 q; q.x = pk[0]; q.y = pk[1]; q.z = pk[2]; q.w = pk[3];
        *(uint4*)(Albase + px*128 + ((g << 4) ^ (((px >> 1) & 7) << 4))) = q;
    }
    __syncthreads();

    // ---- conv1 MFMA: M=32px/wave, N=128, K=64 ----
    f32x4 acc[2][8];
#pragma unroll
    for (int mm = 0; mm < 2; ++mm)
#pragma unroll
        for (int nf = 0; nf < 8; ++nf) acc[mm][nf] = (f32x4){0.f,0.f,0.f,0.f};

    const int px0 = wv*32 + lr;
    const int px1 = px0 + 16;
#pragma unroll
    for (int ks = 0; ks < 2; ++ks) {
        UBF a0, a1;
        a0.u = *(const uint4*)(Albase + px0*128 + ((ks*64 + kg*16) ^ (((px0 >> 1) & 7) << 4)));
        a1.u = *(const uint4*)(Albase + px1*128 + ((ks*64 + kg*16) ^ (((px1 >> 1) & 7) << 4)));
        const char* wp = (const char*)W1f + ks*8192 + lane*16;
#pragma unroll
        for (int nf = 0; nf < 8; ++nf) {
            UBF bf; bf.u = *(const uint4*)(wp + nf*1024);
            acc[0][nf] = __builtin_amdgcn_mfma_f32_16x16x32_bf16(a0.b, bf.b, acc[0][nf], 0, 0, 0);
            acc[1][nf] = __builtin_amdgcn_mfma_f32_16x16x32_bf16(a1.b, bf.b, acc[1][nf], 0, 0, 0);
        }
    }

    // ---- h1 = relu(conv1+b1) -> LDS [px][co] bf16 swizzled ----
    float b1v[8];
#pragma unroll
    for (int nf = 0; nf < 8; ++nf) b1v[nf] = b1[nf*16 + lr];
#pragma unroll
    for (int mm = 0; mm < 2; ++mm)
#pragma unroll
        for (int nf = 0; nf < 8; ++nf) {
            int co2 = (nf*16 + lr) * 2;
#pragma unroll
            for (int rg = 0; rg < 4; ++rg) {
                int px = wv*32 + mm*16 + kg*4 + rg;
                float v = fmaxf(acc[mm][nf][rg] + b1v[nf], 0.f);
                *(ushort*)(h1 + px*256 + (co2 ^ (((px >> 1) & 7) << 4))) = f2bf(v);
            }
        }
    __syncthreads();

    // ---- conv2 MFMA: K=128 ----
#pragma unroll
    for (int mm = 0; mm < 2; ++mm)
#pragma unroll
        for (int nf = 0; nf < 8; ++nf) acc[mm][nf] = (f32x4){0.f,0.f,0.f,0.f};
#pragma unroll
    for (int ks = 0; ks < 4; ++ks) {
        UBF a0, a1;
        a0.u = *(const uint4*)(h1 + px0*256 + ((ks*64 + kg*16) ^ (((px0 >> 1) & 7) << 4)));
        a1.u = *(const uint4*)(h1 + px1*256 + ((ks*64 + kg*16) ^ (((px1 >> 1) & 7) << 4)));
        const char* wp = (const char*)W2f + ks*8192 + lane*16;
#pragma unroll
        for (int nf = 0; nf < 8; ++nf) {
            UBF bf; bf.u = *(const uint4*)(wp + nf*1024);
            acc[0][nf] = __builtin_amdgcn_mfma_f32_16x16x32_bf16(a0.b, bf.b, acc[0][nf], 0, 0, 0);
            acc[1][nf] = __builtin_amdgcn_mfma_f32_16x16x32_bf16(a1.b, bf.b, acc[1][nf], 0, 0, 0);
        }
    }

    __syncthreads();   // all A_lds reads done (buf1 about to be reused as h2st)

    // ---- h2 = relu(conv2+b2) -> staging LDS (swizzled) ----
    float b2v[8];
#pragma unroll
    for (int nf = 0; nf < 8; ++nf) b2v[nf] = b2[nf*16 + lr];
#pragma unroll
    for (int mm = 0; mm < 2; ++mm)
#pragma unroll
        for (int nf = 0; nf < 8; ++nf) {
            int co2 = (nf*16 + lr) * 2;
#pragma unroll
            for (int rg = 0; rg < 4; ++rg) {
                int px = wv*32 + mm*16 + kg*4 + rg;
                float v = fmaxf(acc[mm][nf][rg] + b2v[nf], 0.f);
                *(ushort*)(h2st + px*256 + (co2 ^ (((px >> 1) & 7) << 4))) = f2bf(v);
            }
        }
    __syncthreads();

    // ---- coalesced copy: 32KB tile is contiguous in h2 ----
    const size_t outbase = (size_t)((b*HH + h)*WW) * HID;
    for (int c = tid; c < 2048; c += 256) {
        int px = c >> 4; int cb = (c & 15) << 4;
        uint4 v = *(const uint4*)(h2st + px*256 + (cb ^ (((px >> 1) & 7) << 4)));
        *(uint4*)&h2[outbase + (size_t)c*8] = v;
    }
}

// ---------------- conv3 (MFMA bf16) + spline + identity copy + objective ----------------
// block: (wtile 0..1, h, b); 256 thr = 4 waves; wave = 32px x 32co (2x2 frag grid)
__global__ __launch_bounds__(256) void k_conv3_spline(
    const float* __restrict__ x,
    const ushort* __restrict__ h2,
    const ushort* __restrict__ Wfrag, const float* __restrict__ b3,
    float* __restrict__ out, float* __restrict__ obj)
{
    __shared__ char xsb[3*66*256];      // 50688B; A-tile, later overlaid by params [64][68] f32
    __shared__ float red[4];

    const int w0 = blockIdx.x * 64;
    const int h  = blockIdx.y;
    const int b  = blockIdx.z;
    const int tid = threadIdx.x;

    // ---- prologue: identity copy + transform-x prefetch (pure HBM, hides latency) ----
    float xr1, xr2 = 0.f;
    {
        const int c1 = tid >> 6;            // 0..3
        const int p1 = tid & 63;
        const size_t base1 = ((size_t)(b*CFULL + c1)*HH + h)*WW + w0 + p1;
        out[base1] = x[base1];
        xr1 = x[base1 + (size_t)CH*HH*WW];
        if (tid < 128) {
            const int c2 = 4 + (tid >> 6);
            const size_t base2 = ((size_t)(b*CFULL + c2)*HH + h)*WW + w0 + p1;
            out[base2] = x[base2];
            xr2 = x[base2 + (size_t)CH*HH*WW];
        }
    }

    // ---- stage h2 tile: 3 rows x 66 w x 128 ci ----
    for (int i = tid; i < 3*66*16; i += 256) {
        int r = i / 1056; int rem = i - r*1056;
        int wl = rem >> 4; int c16 = rem & 15;
        int hh = h + r - 1, ww = w0 + wl - 1;
        uint4 v = {0,0,0,0};
        if (hh >= 0 && hh < HH && ww >= 0 && ww < WW)
            v = *(const uint4*)&h2[(size_t)((b*HH + hh)*WW + ww) * HID + c16*8];
        int swz = (wl & 7) << 4;
        *(uint4*)(xsb + (r*66 + wl)*256 + ((c16*16) ^ swz)) = v;
    }
    __syncthreads();

    // ---- MFMA: wave = (mrow, ncol) in 2x2; frags acc[mm][nn] = (32px x 32co)/wave ----
    const int lane = tid & 63;
    const int wv   = tid >> 6;
    const int kg   = lane >> 4;
    const int lr   = lane & 15;
    const int mrow = wv >> 1;           // 0..1 : px half
    const int ncol = wv & 1;            // 0..1 : co half

    f32x4 acc[2][2];
#pragma unroll
    for (int mm = 0; mm < 2; ++mm)
#pragma unroll
        for (int nn = 0; nn < 2; ++nn) acc[mm][nn] = (f32x4){0.f,0.f,0.f,0.f};

    const char* wbase = (const char*)Wfrag + ncol*2048 + lane*16;

#pragma unroll 1
    for (int r = 0; r < 3; ++r) {
#pragma unroll
        for (int dx = 0; dx < 3; ++dx) {
            const int t = r*3 + dx;
            const int wl0 = mrow*32 + lr + dx;
            const int wl1 = wl0 + 16;
            const int swz = (wl0 & 7) << 4;   // wl1 has same low-3 bits
            const int row0 = (r*66 + wl0) << 8;
            const int row1 = (r*66 + wl1) << 8;
#pragma unroll
            for (int kb = 0; kb < 4; ++kb) {
                const int ko = ((kb << 6) + (kg << 4)) ^ swz;
                UBF a0; a0.u = *(const uint4*)(xsb + row0 + ko);
                UBF a1; a1.u = *(const uint4*)(xsb + row1 + ko);
                const char* wp = wbase + (((t << 2) + kb) << 12);
                UBF b0; b0.u = *(const uint4*)(wp);
                UBF b1; b1.u = *(const uint4*)(wp + 1024);
                acc[0][0] = __builtin_amdgcn_mfma_f32_16x16x32_bf16(a0.b, b0.b, acc[0][0], 0, 0, 0);
                acc[0][1] = __builtin_amdgcn_mfma_f32_16x16x32_bf16(a0.b, b1.b, acc[0][1], 0, 0, 0);
                acc[1][0] = __builtin_amdgcn_mfma_f32_16x16x32_bf16(a1.b, b0.b, acc[1][0], 0, 0, 0);
                acc[1][1] = __builtin_amdgcn_mfma_f32_16x16x32_bf16(a1.b, b1.b, acc[1][1], 0, 0, 0);
            }
        }
    }

    __syncthreads();    // all xs reads done; overlay params tile

    // ---- params [co][px] f32, stride 68, overlaid on xsb ----
    float* pl = (float*)xsb;
#pragma unroll
    for (int mm = 0; mm < 2; ++mm)
#pragma unroll
        for (int nn = 0; nn < 2; ++nn) {
            const int row = (ncol*2 + nn)*16 + lr;
            const int px0 = (mrow*2 + mm)*16 + (kg << 2);
            *(f32x4*)&pl[row*68 + px0] = acc[mm][nn];
        }
    __syncthreads();

    // ---- spline ----
    float lad = 0.f;
#pragma unroll
    for (int half = 0; half < 2; ++half) {
        const int i = tid + half*256;
        if (i >= 384) break;
        const int c  = __builtin_amdgcn_readfirstlane(i >> 6);
        const int px = i & 63;
        const int wg = w0 + px;
        const float xraw = half ? xr2 : xr1;

        float u[9];
#pragma unroll
        for (int j = 0; j < 9; ++j) u[j] = pl[(c*9 + j)*68 + px] + b3[c*9 + j];

        bool inside = (xraw >= -1.f) && (xraw <= 1.f);
        float xc = fminf(fmaxf(xraw, -1.f), 1.f);
        float in01 = (xc + 1.f) * 0.5f;

        float m = u[0];
#pragma unroll
        for (int i2 = 1; i2 < 5; ++i2) m = fmaxf(m, u[i2]);
        float e[5], es = 0.f;
#pragma unroll
        for (int i2 = 0; i2 < 5; ++i2) { e[i2] = expf(u[i2] - m); es += e[i2]; }
        float wdt[5];
#pragma unroll
        for (int i2 = 0; i2 < 5; ++i2) wdt[i2] = 0.001f + (1.f - 0.001f*NB) * (e[i2] / es);

        float eh[4];
#pragma unroll
        for (int i2 = 0; i2 < 4; ++i2) eh[i2] = expf(u[5 + i2]);

        float first_w = 0.5f * wdt[0], last_w = 0.5f * wdt[4];
        float numer = 0.5f*first_w*eh[0] + 0.5f*last_w*eh[3]
                    + 0.5f*(eh[0]+eh[1])*wdt[1]
                    + 0.5f*(eh[1]+eh[2])*wdt[2]
                    + 0.5f*(eh[2]+eh[3])*wdt[3];
        float cst = numer / (1.f - 0.5f*first_w - 0.5f*last_w);

        float kn[6] = {cst, eh[0], eh[1], eh[2], eh[3], cst};
        float area = 0.f;
#pragma unroll
        for (int i2 = 0; i2 < 5; ++i2) area += 0.5f*(kn[i2]+kn[i2+1])*wdt[i2];
        float hts[6];
#pragma unroll
        for (int i2 = 0; i2 < 6; ++i2) hts[i2] = 0.001f + (1.f - 0.001f) * (kn[i2] / area);

        float C[6]; C[0] = 0.f;
#pragma unroll
        for (int i2 = 0; i2 < 5; ++i2) C[i2+1] = C[i2] + 0.5f*(hts[i2]+hts[i2+1])*wdt[i2];
        C[5] = 1.f;
        float L[6]; L[0] = 0.f;
#pragma unroll
        for (int i2 = 0; i2 < 5; ++i2) L[i2+1] = L[i2] + wdt[i2];
        L[5] = 1.f;

        int idx = 0;
#pragma unroll
        for (int i2 = 1; i2 < 6; ++i2) idx += (in01 >= L[i2]) ? 1 : 0;
        idx = min(idx, 4);

        float loc = L[0], cdf = C[0], hl = hts[0], hr = hts[1], wb2 = wdt[0];
#pragma unroll
        for (int i2 = 1; i2 < 5; ++i2) {
            if (i2 == idx) { loc = L[i2]; cdf = C[i2]; hl = hts[i2]; hr = hts[i2+1]; wb2 = wdt[i2]; }
        }

        float alpha = (in01 - loc) / wb2;
        float aa = 0.5f*(hr - hl)*wb2;
        float bb = hl*wb2;
        float o = fminf(fmaxf(aa*alpha*alpha + bb*alpha + cdf, 0.f), 1.f);
        float sl = logf(alpha*(hr - hl) + hl);
        float outv = o*2.f - 1.f;
        if (!inside) { outv = xraw; sl = 0.f; }
        out[((b*CFULL + CH + c)*HH + h)*WW + wg] = outv;
        lad += sl;
    }

#pragma unroll
    for (int off = 32; off > 0; off >>= 1) lad += __shfl_down(lad, off, 64);
    if ((tid & 63) == 0) red[tid >> 6] = lad;
    __syncthreads();
    if (tid == 0) {
        float s = red[0] + red[1] + red[2] + red[3];
        atomicAdd(&obj[b], s);
    }
}

extern "C" void kernel_launch(void* const* d_in, const int* in_sizes, int n_in,
                              void* d_out, int out_size, void* d_ws, size_t ws_size,
                              hipStream_t stream) {
    const float* x   = (const float*)d_in[0];
    const float* obj = (const float*)d_in[1];
    const float* w1  = (const float*)d_in[2];
    const float* b1  = (const float*)d_in[3];
    const float* w2  = (const float*)d_in[4];
    const float* b2  = (const float*)d_in[5];
    const float* w3  = (const float*)d_in[6];
    const float* b3  = (const float*)d_in[7];

    float* out_t = (float*)d_out;
    float* obj_o = out_t + OUT_ELEMS;
    ushort* h2  = (ushort*)d_ws;
    ushort* W3f = (ushort*)((char*)d_ws + H2_BYTES);
    ushort* W1f = (ushort*)((char*)d_ws + H2_BYTES + 147456);
    ushort* W2f = (ushort*)((char*)d_ws + H2_BYTES + 147456 + 16384);

    k_init_obj<<<1, 64, 0, stream>>>(obj, obj_o);
    k_prep<<<(WFRAG_ELEMS + 255)/256, 256, 0, stream>>>(w3, W3f);
    k_prep12<<<(W1F_ELEMS + W2F_ELEMS + 255)/256, 256, 0, stream>>>(w1, w2, W1f, W2f);
    k_conv12<<<B*HH, 256, 0, stream>>>(x, W1f, b1, W2f, b2, h2);
    k_conv3_spline<<<dim3(2, HH, B), 256, 0, stream>>>(x, h2, W3f, b3, out_t, obj_o);
}

// Round 5
// 377.358 us; speedup vs baseline: 9.1114x; 1.0779x over previous
//
#include <hip/hip_runtime.h>
#include <hip/hip_bf16.h>
#include <math.h>

#define B 32
#define CFULL 12
#define CH 6
#define HH 128
#define WW 128
#define HID 128
#define CO3 54
#define NB 5
#define OUT_ELEMS (B*CFULL*HH*WW)
#define H2_BYTES (size_t)(B*HH*WW*HID*2)        // bf16 channels-last [b][h][w][ci]
#define WFRAG_ELEMS (9*4*4*64*8)                 // w3 frags: 73728 bf16
#define W1F_ELEMS (2*8*64*8)                     // 8192
#define W2F_ELEMS (4*8*64*8)                     // 16384

typedef __bf16 bf16x8 __attribute__((ext_vector_type(8)));
typedef float f32x4 __attribute__((ext_vector_type(4)));

__device__ __forceinline__ ushort f2bf(float f) {
    uint b = __float_as_uint(f);
    uint r = (b + 0x7FFFu + ((b >> 16) & 1u)) >> 16;
    return (ushort)r;
}

union UBF { uint4 u; bf16x8 b; };

// ---------------- combined prep: objective copy + w1/w2/w3 fragment layouts ----------------
__global__ __launch_bounds__(256) void k_prep_all(
    const float* __restrict__ w1, const float* __restrict__ w2, const float* __restrict__ w3,
    const float* __restrict__ obj_in, float* __restrict__ obj_out,
    ushort* __restrict__ W1f, ushort* __restrict__ W2f, ushort* __restrict__ W3f)
{
    int idx = blockIdx.x * 256 + threadIdx.x;
    if (blockIdx.x == 0 && threadIdx.x < B) obj_out[threadIdx.x] = obj_in[threadIdx.x];

    if (idx < WFRAG_ELEMS) {
        int j    = idx & 7;
        int lane = (idx >> 3) & 63;
        int nf   = (idx >> 9) & 3;
        int kb   = (idx >> 11) & 3;
        int t    = idx >> 13;
        int co = nf * 16 + (lane & 15);
        int ci = kb * 32 + 8 * (lane >> 4) + j;
        float v = (co < CO3) ? w3[(co * HID + ci) * 9 + t] : 0.f;
        W3f[idx] = f2bf(v);
    } else if (idx < WFRAG_ELEMS + W1F_ELEMS) {
        int i1 = idx - WFRAG_ELEMS;
        int j = i1 & 7, lane = (i1 >> 3) & 63, nf = (i1 >> 9) & 7, ks = i1 >> 12;
        int co = nf * 16 + (lane & 15);
        int k  = ks * 32 + (lane >> 4) * 8 + j;
        W1f[i1] = f2bf(k < 54 ? w1[co * 54 + k] : 0.f);
    } else if (idx < WFRAG_ELEMS + W1F_ELEMS + W2F_ELEMS) {
        int i2 = idx - WFRAG_ELEMS - W1F_ELEMS;
        int j = i2 & 7, lane = (i2 >> 3) & 63, nf = (i2 >> 9) & 7, ks = (i2 >> 12) & 3;
        int co = nf * 16 + (lane & 15);
        int ci = ks * 32 + (lane >> 4) * 8 + j;
        W2f[i2] = f2bf(w2[co * 128 + ci]);
    }
}

// ---------------- conv1+conv2 via MFMA, writes h2 bf16 channels-last ----------------
__global__ __launch_bounds__(256) void k_conv12(
    const float* __restrict__ x,
    const ushort* __restrict__ W1f, const float* __restrict__ b1,
    const ushort* __restrict__ W2f, const float* __restrict__ b2,
    ushort* __restrict__ h2)
{
    __shared__ char buf1[21248];   // xs bf16 (4752B @0) + A_lds (16KB @4864)
    __shared__ char buf2[32768];   // h1 [128px][128co] bf16 swizzled; later h2 staging

    ushort* xs = (ushort*)buf1;               // [6][3][132] bf16
    char* Albase = buf1 + 4864;               // A [128px][64k] bf16 swizzled
    char* h1 = buf2;
    char* h2st = buf2;

    const int b = blockIdx.x >> 7;
    const int h = blockIdx.x & 127;
    const int tid = threadIdx.x;
    const int lane = tid & 63;
    const int wv = tid >> 6;        // 0..3
    const int lr = lane & 15;
    const int kg = lane >> 4;       // 0..3

    // ---- stage x rows: 6ch x 3r x 130w (as bf16) ----
    for (int i = tid; i < 6*3*130; i += 256) {
        int ci = i / 390; int rem = i - ci*390;
        int r = rem / 130; int xw = rem - r*130;
        int hh = h + r - 1, ww = xw - 1;
        float v = 0.f;
        if (hh >= 0 && hh < HH && ww >= 0 && ww < WW)
            v = x[((b*CFULL + ci)*HH + hh)*WW + ww];
        xs[(ci*3 + r)*132 + xw] = f2bf(v);
    }
    __syncthreads();

    // ---- build im2col A: [128px][64k], k = ci*9 + r*3 + dx (54 used) ----
    for (int it = 0; it < 4; ++it) {
        int item = (it << 8) + tid;          // 1024 items
        int px = item & 127;
        int g  = item >> 7;                  // 0..7
        uint pk[4];
#pragma unroll
        for (int jj = 0; jj < 4; ++jj) {
            int k0 = g*8 + jj*2;
            int k1 = k0 + 1;
            uint v0 = 0, v1 = 0;
            if (k0 < 54) { int ci = k0/9; int rem = k0 - ci*9; int r = rem/3; int dx = rem - r*3;
                           v0 = xs[(ci*3 + r)*132 + px + dx]; }
            if (k1 < 54) { int ci = k1/9; int rem = k1 - ci*9; int r = rem/3; int dx = rem - r*3;
                           v1 = xs[(ci*3 + r)*132 + px + dx]; }
            pk[jj] = v0 | (v1 << 16);
        }
        uint4 q; q.x = pk[0]; q.y = pk[1]; q.z = pk[2]; q.w = pk[3];
        *(uint4*)(Albase + px*128 + ((g << 4) ^ (((px >> 1) & 7) << 4))) = q;
    }
    __syncthreads();

    // ---- conv1 MFMA: M=32px/wave, N=128, K=64 ----
    f32x4 acc[2][8];
#pragma unroll
    for (int mm = 0; mm < 2; ++mm)
#pragma unroll
        for (int nf = 0; nf < 8; ++nf) acc[mm][nf] = (f32x4){0.f,0.f,0.f,0.f};

    const int px0 = wv*32 + lr;
    const int px1 = px0 + 16;
#pragma unroll
    for (int ks = 0; ks < 2; ++ks) {
        UBF a0, a1;
        a0.u = *(const uint4*)(Albase + px0*128 + ((ks*64 + kg*16) ^ (((px0 >> 1) & 7) << 4)));
        a1.u = *(const uint4*)(Albase + px1*128 + ((ks*64 + kg*16) ^ (((px1 >> 1) & 7) << 4)));
        const char* wp = (const char*)W1f + ks*8192 + lane*16;
#pragma unroll
        for (int nf = 0; nf < 8; ++nf) {
            UBF bf; bf.u = *(const uint4*)(wp + nf*1024);
            acc[0][nf] = __builtin_amdgcn_mfma_f32_16x16x32_bf16(a0.b, bf.b, acc[0][nf], 0, 0, 0);
            acc[1][nf] = __builtin_amdgcn_mfma_f32_16x16x32_bf16(a1.b, bf.b, acc[1][nf], 0, 0, 0);
        }
    }

    // ---- h1 = relu(conv1+b1) -> LDS [px][co] bf16 swizzled ----
    float b1v[8];
#pragma unroll
    for (int nf = 0; nf < 8; ++nf) b1v[nf] = b1[nf*16 + lr];
#pragma unroll
    for (int mm = 0; mm < 2; ++mm)
#pragma unroll
        for (int nf = 0; nf < 8; ++nf) {
            int co2 = (nf*16 + lr) * 2;
#pragma unroll
            for (int rg = 0; rg < 4; ++rg) {
                int px = wv*32 + mm*16 + kg*4 + rg;
                float v = fmaxf(acc[mm][nf][rg] + b1v[nf], 0.f);
                *(ushort*)(h1 + px*256 + (co2 ^ (((px >> 1) & 7) << 4))) = f2bf(v);
            }
        }
    __syncthreads();

    // ---- conv2 MFMA: K=128 ----
#pragma unroll
    for (int mm = 0; mm < 2; ++mm)
#pragma unroll
        for (int nf = 0; nf < 8; ++nf) acc[mm][nf] = (f32x4){0.f,0.f,0.f,0.f};
#pragma unroll
    for (int ks = 0; ks < 4; ++ks) {
        UBF a0, a1;
        a0.u = *(const uint4*)(h1 + px0*256 + ((ks*64 + kg*16) ^ (((px0 >> 1) & 7) << 4)));
        a1.u = *(const uint4*)(h1 + px1*256 + ((ks*64 + kg*16) ^ (((px1 >> 1) & 7) << 4)));
        const char* wp = (const char*)W2f + ks*8192 + lane*16;
#pragma unroll
        for (int nf = 0; nf < 8; ++nf) {
            UBF bf; bf.u = *(const uint4*)(wp + nf*1024);
            acc[0][nf] = __builtin_amdgcn_mfma_f32_16x16x32_bf16(a0.b, bf.b, acc[0][nf], 0, 0, 0);
            acc[1][nf] = __builtin_amdgcn_mfma_f32_16x16x32_bf16(a1.b, bf.b, acc[1][nf], 0, 0, 0);
        }
    }

    __syncthreads();   // all h1 reads done (buf2 about to be reused as h2st)

    // ---- h2 = relu(conv2+b2) -> staging LDS (swizzled, overlays h1) ----
    float b2v[8];
#pragma unroll
    for (int nf = 0; nf < 8; ++nf) b2v[nf] = b2[nf*16 + lr];
#pragma unroll
    for (int mm = 0; mm < 2; ++mm)
#pragma unroll
        for (int nf = 0; nf < 8; ++nf) {
            int co2 = (nf*16 + lr) * 2;
#pragma unroll
            for (int rg = 0; rg < 4; ++rg) {
                int px = wv*32 + mm*16 + kg*4 + rg;
                float v = fmaxf(acc[mm][nf][rg] + b2v[nf], 0.f);
                *(ushort*)(h2st + px*256 + (co2 ^ (((px >> 1) & 7) << 4))) = f2bf(v);
            }
        }
    __syncthreads();

    // ---- coalesced copy: 32KB tile is contiguous in h2 ----
    const size_t outbase = (size_t)((b*HH + h)*WW) * HID;
    for (int c = tid; c < 2048; c += 256) {
        int px = c >> 4; int cb = (c & 15) << 4;
        uint4 v = *(const uint4*)(h2st + px*256 + (cb ^ (((px >> 1) & 7) << 4)));
        *(uint4*)&h2[outbase + (size_t)c*8] = v;
    }
}

// ---------------- conv3 (MFMA bf16, k-split) + spline + identity copy + objective ----------------
// block: (wtile 0..1, h, b); 256 thr = 4 waves; wave = 32px x 32co (2x2 frag grid)
// A-tile staged in 2 ci-halves (64 ci each) to halve LDS -> 6 blocks/CU
__global__ __launch_bounds__(256) void k_conv3_spline(
    const float* __restrict__ x,
    const ushort* __restrict__ h2,
    const ushort* __restrict__ Wfrag, const float* __restrict__ b3,
    float* __restrict__ out, float* __restrict__ obj)
{
    __shared__ char xsb[3*66*128];      // 25344B; A half-tile, later overlaid by params [64][68] f32
    __shared__ float red[4];

    const int w0 = blockIdx.x * 64;
    const int h  = blockIdx.y;
    const int b  = blockIdx.z;
    const int tid = threadIdx.x;

    // ---- prologue: identity copy + transform-x prefetch (pure HBM, hides latency) ----
    float xr1, xr2 = 0.f;
    {
        const int c1 = tid >> 6;            // 0..3
        const int p1 = tid & 63;
        const size_t base1 = ((size_t)(b*CFULL + c1)*HH + h)*WW + w0 + p1;
        out[base1] = x[base1];
        xr1 = x[base1 + (size_t)CH*HH*WW];
        if (tid < 128) {
            const int c2 = 4 + (tid >> 6);
            const size_t base2 = ((size_t)(b*CFULL + c2)*HH + h)*WW + w0 + p1;
            out[base2] = x[base2];
            xr2 = x[base2 + (size_t)CH*HH*WW];
        }
    }

    const int lane = tid & 63;
    const int wv   = tid >> 6;
    const int kg   = lane >> 4;
    const int lr   = lane & 15;
    const int mrow = wv >> 1;           // 0..1 : px half
    const int ncol = wv & 1;            // 0..1 : co half

    f32x4 acc[2][2];
#pragma unroll
    for (int mm = 0; mm < 2; ++mm)
#pragma unroll
        for (int nn = 0; nn < 2; ++nn) acc[mm][nn] = (f32x4){0.f,0.f,0.f,0.f};

    const char* wbase = (const char*)Wfrag + ncol*2048 + lane*16;

#pragma unroll 1
    for (int kh = 0; kh < 2; ++kh) {
        if (kh) __syncthreads();        // protect buffer from previous half's readers

        // ---- stage h2 half-tile: 3 rows x 66 w x 64 ci ----
        for (int i = tid; i < 3*66*8; i += 256) {
            int r = i / 528; int rem = i - r*528;
            int wl = rem >> 3; int c8 = rem & 7;
            int hh = h + r - 1, ww = w0 + wl - 1;
            uint4 v = {0,0,0,0};
            if (hh >= 0 && hh < HH && ww >= 0 && ww < WW)
                v = *(const uint4*)&h2[(size_t)((b*HH + hh)*WW + ww) * HID + kh*64 + c8*8];
            int swz = (wl & 7) << 4;
            *(uint4*)(xsb + (r*66 + wl)*128 + ((c8*16) ^ swz)) = v;
        }
        __syncthreads();

        // ---- MFMA over 9 taps x 2 k-blocks ----
#pragma unroll 1
        for (int r = 0; r < 3; ++r) {
#pragma unroll
            for (int dx = 0; dx < 3; ++dx) {
                const int t = r*3 + dx;
                const int wl0 = mrow*32 + lr + dx;
                const int wl1 = wl0 + 16;
                const int swz = (wl0 & 7) << 4;   // wl1 has same low-3 bits
                const int row0 = (r*66 + wl0) << 7;
                const int row1 = (r*66 + wl1) << 7;
#pragma unroll
                for (int kb = 0; kb < 2; ++kb) {
                    const int ko = ((kb << 6) + (kg << 4)) ^ swz;
                    UBF a0; a0.u = *(const uint4*)(xsb + row0 + ko);
                    UBF a1; a1.u = *(const uint4*)(xsb + row1 + ko);
                    const int kbg = kh*2 + kb;
                    const char* wp = wbase + (((t << 2) + kbg) << 12);
                    UBF b0; b0.u = *(const uint4*)(wp);
                    UBF b1; b1.u = *(const uint4*)(wp + 1024);
                    acc[0][0] = __builtin_amdgcn_mfma_f32_16x16x32_bf16(a0.b, b0.b, acc[0][0], 0, 0, 0);
                    acc[0][1] = __builtin_amdgcn_mfma_f32_16x16x32_bf16(a0.b, b1.b, acc[0][1], 0, 0, 0);
                    acc[1][0] = __builtin_amdgcn_mfma_f32_16x16x32_bf16(a1.b, b0.b, acc[1][0], 0, 0, 0);
                    acc[1][1] = __builtin_amdgcn_mfma_f32_16x16x32_bf16(a1.b, b1.b, acc[1][1], 0, 0, 0);
                }
            }
        }
    }

    __syncthreads();    // all xs reads done; overlay params tile

    // ---- params [co][px] f32, stride 68, overlaid on xsb ----
    float* pl = (float*)xsb;
#pragma unroll
    for (int mm = 0; mm < 2; ++mm)
#pragma unroll
        for (int nn = 0; nn < 2; ++nn) {
            const int row = (ncol*2 + nn)*16 + lr;
            const int px0 = (mrow*2 + mm)*16 + (kg << 2);
            *(f32x4*)&pl[row*68 + px0] = acc[mm][nn];
        }
    __syncthreads();

    // ---- spline ----
    float lad = 0.f;
#pragma unroll
    for (int half = 0; half < 2; ++half) {
        const int i = tid + half*256;
        if (i >= 384) break;
        const int c  = __builtin_amdgcn_readfirstlane(i >> 6);
        const int px = i & 63;
        const int wg = w0 + px;
        const float xraw = half ? xr2 : xr1;

        float u[9];
#pragma unroll
        for (int j = 0; j < 9; ++j) u[j] = pl[(c*9 + j)*68 + px] + b3[c*9 + j];

        bool inside = (xraw >= -1.f) && (xraw <= 1.f);
        float xc = fminf(fmaxf(xraw, -1.f), 1.f);
        float in01 = (xc + 1.f) * 0.5f;

        float m = u[0];
#pragma unroll
        for (int i2 = 1; i2 < 5; ++i2) m = fmaxf(m, u[i2]);
        float e[5], es = 0.f;
#pragma unroll
        for (int i2 = 0; i2 < 5; ++i2) { e[i2] = expf(u[i2] - m); es += e[i2]; }
        float wdt[5];
#pragma unroll
        for (int i2 = 0; i2 < 5; ++i2) wdt[i2] = 0.001f + (1.f - 0.001f*NB) * (e[i2] / es);

        float eh[4];
#pragma unroll
        for (int i2 = 0; i2 < 4; ++i2) eh[i2] = expf(u[5 + i2]);

        float first_w = 0.5f * wdt[0], last_w = 0.5f * wdt[4];
        float numer = 0.5f*first_w*eh[0] + 0.5f*last_w*eh[3]
                    + 0.5f*(eh[0]+eh[1])*wdt[1]
                    + 0.5f*(eh[1]+eh[2])*wdt[2]
                    + 0.5f*(eh[2]+eh[3])*wdt[3];
        float cst = numer / (1.f - 0.5f*first_w - 0.5f*last_w);

        float kn[6] = {cst, eh[0], eh[1], eh[2], eh[3], cst};
        float area = 0.f;
#pragma unroll
        for (int i2 = 0; i2 < 5; ++i2) area += 0.5f*(kn[i2]+kn[i2+1])*wdt[i2];
        float hts[6];
#pragma unroll
        for (int i2 = 0; i2 < 6; ++i2) hts[i2] = 0.001f + (1.f - 0.001f) * (kn[i2] / area);

        float C[6]; C[0] = 0.f;
#pragma unroll
        for (int i2 = 0; i2 < 5; ++i2) C[i2+1] = C[i2] + 0.5f*(hts[i2]+hts[i2+1])*wdt[i2];
        C[5] = 1.f;
        float L[6]; L[0] = 0.f;
#pragma unroll
        for (int i2 = 0; i2 < 5; ++i2) L[i2+1] = L[i2] + wdt[i2];
        L[5] = 1.f;

        int idx = 0;
#pragma unroll
        for (int i2 = 1; i2 < 6; ++i2) idx += (in01 >= L[i2]) ? 1 : 0;
        idx = min(idx, 4);

        float loc = L[0], cdf = C[0], hl = hts[0], hr = hts[1], wb2 = wdt[0];
#pragma unroll
        for (int i2 = 1; i2 < 5; ++i2) {
            if (i2 == idx) { loc = L[i2]; cdf = C[i2]; hl = hts[i2]; hr = hts[i2+1]; wb2 = wdt[i2]; }
        }

        float alpha = (in01 - loc) / wb2;
        float aa = 0.5f*(hr - hl)*wb2;
        float bb = hl*wb2;
        float o = fminf(fmaxf(aa*alpha*alpha + bb*alpha + cdf, 0.f), 1.f);
        float sl = logf(alpha*(hr - hl) + hl);
        float outv = o*2.f - 1.f;
        if (!inside) { outv = xraw; sl = 0.f; }
        out[((b*CFULL + CH + c)*HH + h)*WW + wg] = outv;
        lad += sl;
    }

#pragma unroll
    for (int off = 32; off > 0; off >>= 1) lad += __shfl_down(lad, off, 64);
    if ((tid & 63) == 0) red[tid >> 6] = lad;
    __syncthreads();
    if (tid == 0) {
        float s = red[0] + red[1] + red[2] + red[3];
        atomicAdd(&obj[b], s);
    }
}

extern "C" void kernel_launch(void* const* d_in, const int* in_sizes, int n_in,
                              void* d_out, int out_size, void* d_ws, size_t ws_size,
                              hipStream_t stream) {
    const float* x   = (const float*)d_in[0];
    const float* obj = (const float*)d_in[1];
    const float* w1  = (const float*)d_in[2];
    const float* b1  = (const float*)d_in[3];
    const float* w2  = (const float*)d_in[4];
    const float* b2  = (const float*)d_in[5];
    const float* w3  = (const float*)d_in[6];
    const float* b3  = (const float*)d_in[7];

    float* out_t = (float*)d_out;
    float* obj_o = out_t + OUT_ELEMS;
    ushort* h2  = (ushort*)d_ws;
    ushort* W3f = (ushort*)((char*)d_ws + H2_BYTES);
    ushort* W1f = (ushort*)((char*)d_ws + H2_BYTES + 147456);
    ushort* W2f = (ushort*)((char*)d_ws + H2_BYTES + 147456 + 16384);

    const int prep_items = WFRAG_ELEMS + W1F_ELEMS + W2F_ELEMS;   // 98304
    k_prep_all<<<(prep_items + 255)/256, 256, 0, stream>>>(w1, w2, w3, obj, obj_o, W1f, W2f, W3f);
    k_conv12<<<B*HH, 256, 0, stream>>>(x, W1f, b1, W2f, b2, h2);
    k_conv3_spline<<<dim3(2, HH, B), 256, 0, stream>>>(x, h2, W3f, b3, out_t, obj_o);
}

// Round 6
// 295.257 us; speedup vs baseline: 11.6449x; 1.2781x over previous
//
#include <hip/hip_runtime.h>
#include <hip/hip_bf16.h>
#include <math.h>

#define B 32
#define CFULL 12
#define CH 6
#define HH 128
#define WW 128
#define HID 128
#define CO3 54
#define NB 5
#define OUT_ELEMS (B*CFULL*HH*WW)
#define H2_BYTES (size_t)(B*HH*WW*HID*2)        // bf16 channels-last [b][h][w][ci]
#define WFRAG_ELEMS (9*4*4*64*8)                 // w3 frags: 73728 bf16
#define W1F_ELEMS (2*8*64*8)                     // 8192
#define W2F_ELEMS (4*8*64*8)                     // 16384

typedef __bf16 bf16x8 __attribute__((ext_vector_type(8)));
typedef float f32x4 __attribute__((ext_vector_type(4)));

__device__ __forceinline__ ushort f2bf(float f) {
    uint b = __float_as_uint(f);
    uint r = (b + 0x7FFFu + ((b >> 16) & 1u)) >> 16;
    return (ushort)r;
}

union UBF { uint4 u; bf16x8 b; };

// ---------------- combined prep: objective copy + w1/w2/w3 fragment layouts ----------------
__global__ __launch_bounds__(256) void k_prep_all(
    const float* __restrict__ w1, const float* __restrict__ w2, const float* __restrict__ w3,
    const float* __restrict__ obj_in, float* __restrict__ obj_out,
    ushort* __restrict__ W1f, ushort* __restrict__ W2f, ushort* __restrict__ W3f)
{
    int idx = blockIdx.x * 256 + threadIdx.x;
    if (blockIdx.x == 0 && threadIdx.x < B) obj_out[threadIdx.x] = obj_in[threadIdx.x];

    if (idx < WFRAG_ELEMS) {
        int j    = idx & 7;
        int lane = (idx >> 3) & 63;
        int nf   = (idx >> 9) & 3;
        int kb   = (idx >> 11) & 3;
        int t    = idx >> 13;
        int co = nf * 16 + (lane & 15);
        int ci = kb * 32 + 8 * (lane >> 4) + j;
        float v = (co < CO3) ? w3[(co * HID + ci) * 9 + t] : 0.f;
        W3f[idx] = f2bf(v);
    } else if (idx < WFRAG_ELEMS + W1F_ELEMS) {
        int i1 = idx - WFRAG_ELEMS;
        int j = i1 & 7, lane = (i1 >> 3) & 63, nf = (i1 >> 9) & 7, ks = i1 >> 12;
        int co = nf * 16 + (lane & 15);
        int k  = ks * 32 + (lane >> 4) * 8 + j;
        W1f[i1] = f2bf(k < 54 ? w1[co * 54 + k] : 0.f);
    } else if (idx < WFRAG_ELEMS + W1F_ELEMS + W2F_ELEMS) {
        int i2 = idx - WFRAG_ELEMS - W1F_ELEMS;
        int j = i2 & 7, lane = (i2 >> 3) & 63, nf = (i2 >> 9) & 7, ks = (i2 >> 12) & 3;
        int co = nf * 16 + (lane & 15);
        int ci = ks * 32 + (lane >> 4) * 8 + j;
        W2f[i2] = f2bf(w2[co * 128 + ci]);
    }
}

// ---------------- conv1+conv2 via MFMA, writes h2 bf16 channels-last ----------------
__global__ __launch_bounds__(256) void k_conv12(
    const float* __restrict__ x,
    const ushort* __restrict__ W1f, const float* __restrict__ b1,
    const ushort* __restrict__ W2f, const float* __restrict__ b2,
    ushort* __restrict__ h2)
{
    __shared__ char buf1[21248];   // xs bf16 (4752B @0) + A_lds (16KB @4864)
    __shared__ char buf2[32768];   // h1 [128px][128co] bf16 swizzled; later h2 staging

    ushort* xs = (ushort*)buf1;               // [6][3][132] bf16
    char* Albase = buf1 + 4864;               // A [128px][64k] bf16 swizzled
    char* h1 = buf2;
    char* h2st = buf2;

    const int b = blockIdx.x >> 7;
    const int h = blockIdx.x & 127;
    const int tid = threadIdx.x;
    const int lane = tid & 63;
    const int wv = tid >> 6;        // 0..3
    const int lr = lane & 15;
    const int kg = lane >> 4;       // 0..3

    // ---- stage x rows: 6ch x 3r x 130w (as bf16) ----
    for (int i = tid; i < 6*3*130; i += 256) {
        int ci = i / 390; int rem = i - ci*390;
        int r = rem / 130; int xw = rem - r*130;
        int hh = h + r - 1, ww = xw - 1;
        float v = 0.f;
        if (hh >= 0 && hh < HH && ww >= 0 && ww < WW)
            v = x[((b*CFULL + ci)*HH + hh)*WW + ww];
        xs[(ci*3 + r)*132 + xw] = f2bf(v);
    }
    __syncthreads();

    // ---- build im2col A: [128px][64k], k = ci*9 + r*3 + dx (54 used) ----
    for (int it = 0; it < 4; ++it) {
        int item = (it << 8) + tid;          // 1024 items
        int px = item & 127;
        int g  = item >> 7;                  // 0..7
        uint pk[4];
#pragma unroll
        for (int jj = 0; jj < 4; ++jj) {
            int k0 = g*8 + jj*2;
            int k1 = k0 + 1;
            uint v0 = 0, v1 = 0;
            if (k0 < 54) { int ci = k0/9; int rem = k0 - ci*9; int r = rem/3; int dx = rem - r*3;
                           v0 = xs[(ci*3 + r)*132 + px + dx]; }
            if (k1 < 54) { int ci = k1/9; int rem = k1 - ci*9; int r = rem/3; int dx = rem - r*3;
                           v1 = xs[(ci*3 + r)*132 + px + dx]; }
            pk[jj] = v0 | (v1 << 16);
        }
        uint4 q; q.x = pk[0]; q.y = pk[1]; q.z = pk[2]; q.w = pk[3];
        *(uint4*)(Albase + px*128 + ((g << 4) ^ (((px >> 1) & 7) << 4))) = q;
    }
    __syncthreads();

    // ---- conv1 MFMA: M=32px/wave, N=128, K=64 ----
    f32x4 acc[2][8];
#pragma unroll
    for (int mm = 0; mm < 2; ++mm)
#pragma unroll
        for (int nf = 0; nf < 8; ++nf) acc[mm][nf] = (f32x4){0.f,0.f,0.f,0.f};

    const int px0 = wv*32 + lr;
    const int px1 = px0 + 16;
#pragma unroll
    for (int ks = 0; ks < 2; ++ks) {
        UBF a0, a1;
        a0.u = *(const uint4*)(Albase + px0*128 + ((ks*64 + kg*16) ^ (((px0 >> 1) & 7) << 4)));
        a1.u = *(const uint4*)(Albase + px1*128 + ((ks*64 + kg*16) ^ (((px1 >> 1) & 7) << 4)));
        const char* wp = (const char*)W1f + ks*8192 + lane*16;
#pragma unroll
        for (int nf = 0; nf < 8; ++nf) {
            UBF bf; bf.u = *(const uint4*)(wp + nf*1024);
            acc[0][nf] = __builtin_amdgcn_mfma_f32_16x16x32_bf16(a0.b, bf.b, acc[0][nf], 0, 0, 0);
            acc[1][nf] = __builtin_amdgcn_mfma_f32_16x16x32_bf16(a1.b, bf.b, acc[1][nf], 0, 0, 0);
        }
    }

    // ---- h1 = relu(conv1+b1) -> LDS [px][co] bf16 swizzled ----
    float b1v[8];
#pragma unroll
    for (int nf = 0; nf < 8; ++nf) b1v[nf] = b1[nf*16 + lr];
#pragma unroll
    for (int mm = 0; mm < 2; ++mm)
#pragma unroll
        for (int nf = 0; nf < 8; ++nf) {
            int co2 = (nf*16 + lr) * 2;
#pragma unroll
            for (int rg = 0; rg < 4; ++rg) {
                int px = wv*32 + mm*16 + kg*4 + rg;
                float v = fmaxf(acc[mm][nf][rg] + b1v[nf], 0.f);
                *(ushort*)(h1 + px*256 + (co2 ^ (((px >> 1) & 7) << 4))) = f2bf(v);
            }
        }
    __syncthreads();

    // ---- conv2 MFMA: K=128 ----
#pragma unroll
    for (int mm = 0; mm < 2; ++mm)
#pragma unroll
        for (int nf = 0; nf < 8; ++nf) acc[mm][nf] = (f32x4){0.f,0.f,0.f,0.f};
#pragma unroll
    for (int ks = 0; ks < 4; ++ks) {
        UBF a0, a1;
        a0.u = *(const uint4*)(h1 + px0*256 + ((ks*64 + kg*16) ^ (((px0 >> 1) & 7) << 4)));
        a1.u = *(const uint4*)(h1 + px1*256 + ((ks*64 + kg*16) ^ (((px1 >> 1) & 7) << 4)));
        const char* wp = (const char*)W2f + ks*8192 + lane*16;
#pragma unroll
        for (int nf = 0; nf < 8; ++nf) {
            UBF bf; bf.u = *(const uint4*)(wp + nf*1024);
            acc[0][nf] = __builtin_amdgcn_mfma_f32_16x16x32_bf16(a0.b, bf.b, acc[0][nf], 0, 0, 0);
            acc[1][nf] = __builtin_amdgcn_mfma_f32_16x16x32_bf16(a1.b, bf.b, acc[1][nf], 0, 0, 0);
        }
    }

    __syncthreads();   // all h1 reads done (buf2 about to be reused as h2st)

    // ---- h2 = relu(conv2+b2) -> staging LDS (swizzled, overlays h1) ----
    float b2v[8];
#pragma unroll
    for (int nf = 0; nf < 8; ++nf) b2v[nf] = b2[nf*16 + lr];
#pragma unroll
    for (int mm = 0; mm < 2; ++mm)
#pragma unroll
        for (int nf = 0; nf < 8; ++nf) {
            int co2 = (nf*16 + lr) * 2;
#pragma unroll
            for (int rg = 0; rg < 4; ++rg) {
                int px = wv*32 + mm*16 + kg*4 + rg;
                float v = fmaxf(acc[mm][nf][rg] + b2v[nf], 0.f);
                *(ushort*)(h2st + px*256 + (co2 ^ (((px >> 1) & 7) << 4))) = f2bf(v);
            }
        }
    __syncthreads();

    // ---- coalesced copy: 32KB tile is contiguous in h2 ----
    const size_t outbase = (size_t)((b*HH + h)*WW) * HID;
    for (int c = tid; c < 2048; c += 256) {
        int px = c >> 4; int cb = (c & 15) << 4;
        uint4 v = *(const uint4*)(h2st + px*256 + (cb ^ (((px >> 1) & 7) << 4)));
        *(uint4*)&h2[outbase + (size_t)c*8] = v;
    }
}

// ---------------- conv3 (MFMA bf16) + spline + identity copy + objective ----------------
// block: (row-pair g, b); 256 thr = 4 waves; wave = full row (128px) x 32co
// A-tile: [4 h2rows][132 wl][32 ci] bf16 per ci-quarter, XOR-(wl&3) swizzle
__global__ __launch_bounds__(256, 3) void k_conv3_spline(
    const float* __restrict__ x,
    const ushort* __restrict__ h2,
    const ushort* __restrict__ Wfrag, const float* __restrict__ b3,
    float* __restrict__ out, float* __restrict__ obj)
{
    __shared__ char xsb[33792];         // A quarter-tile; later params pl[64][132] f32 (exact fit)
    __shared__ float red[4];

    const int g = blockIdx.x;           // row pair: rows 2g, 2g+1
    const int b = blockIdx.y;
    const int tid = threadIdx.x;
    const int px = tid & 127;
    const int t7 = (tid >> 7) & 1;

    // ---- prologue: identity copy + transform-x prefetch (pure HBM) ----
    float xr0, xr1, xr2, xr3, xr4, xr5;
    {
        size_t base;
#define PRO(RR, KS, DST) \
        base = ((size_t)(b*CFULL + (t7 + 2*(KS)))*HH + (2*g + (RR)))*WW + px; \
        out[base] = x[base]; \
        DST = x[base + (size_t)CH*HH*WW];
        PRO(0,0,xr0) PRO(0,1,xr1) PRO(0,2,xr2)
        PRO(1,0,xr3) PRO(1,1,xr4) PRO(1,2,xr5)
#undef PRO
    }

    const int lane = tid & 63;
    const int wv   = tid >> 6;
    const int mrow = wv >> 1;           // 0..1 : which output row
    const int ncol = wv & 1;            // 0..1 : co half
    const int kg   = lane >> 4;
    const int lr   = lane & 15;

    f32x4 acc[8][2];
#pragma unroll
    for (int mf = 0; mf < 8; ++mf) {
        acc[mf][0] = (f32x4){0.f,0.f,0.f,0.f};
        acc[mf][1] = (f32x4){0.f,0.f,0.f,0.f};
    }

    const char* wbase = (const char*)Wfrag + ncol*2048 + lane*16;

#pragma unroll 1
    for (int q = 0; q < 4; ++q) {
        if (q) __syncthreads();         // protect tile from previous quarter's readers

        // ---- stage quarter: 4 h2-rows x 130 wl x 32 ci ----
        for (int i = tid; i < 2080; i += 256) {
            int r = i / 520; int rem = i - r*520;
            int wl = rem >> 2; int c4 = rem & 3;
            int hh = 2*g - 1 + r, ww = wl - 1;
            uint4 v = {0,0,0,0};
            if (hh >= 0 && hh < HH && ww >= 0 && ww < WW)
                v = *(const uint4*)&h2[(size_t)((b*HH + hh)*WW + ww)*HID + q*32 + c4*8];
            *(uint4*)(xsb + r*8448 + wl*64 + ((c4*16) ^ ((wl & 3) << 4))) = v;
        }
        __syncthreads();

        // ---- MFMA: 9 taps, K=32 each ----
#pragma unroll 1
        for (int r3 = 0; r3 < 3; ++r3) {
            const char* rowb = xsb + (mrow + r3)*8448;
#pragma unroll
            for (int dx = 0; dx < 3; ++dx) {
                const int t = r3*3 + dx;
                const char* wp = wbase + (((t << 2) + q) << 12);
                UBF b0; b0.u = *(const uint4*)(wp);
                UBF b1; b1.u = *(const uint4*)(wp + 1024);
#pragma unroll
                for (int mf = 0; mf < 8; ++mf) {
                    const int wl = mf*16 + lr + dx;
                    UBF a; a.u = *(const uint4*)(rowb + wl*64 + ((kg*16) ^ ((wl & 3) << 4)));
                    acc[mf][0] = __builtin_amdgcn_mfma_f32_16x16x32_bf16(a.b, b0.b, acc[mf][0], 0, 0, 0);
                    acc[mf][1] = __builtin_amdgcn_mfma_f32_16x16x32_bf16(a.b, b1.b, acc[mf][1], 0, 0, 0);
                }
            }
        }
    }
    __syncthreads();        // A-tile dead; overlay params

    float* pl = (float*)xsb;
    float lad = 0.f;

#pragma unroll
    for (int r = 0; r < 2; ++r) {
        if (r) __syncthreads();         // wait for previous phase's pl readers

        if (mrow == r) {
#pragma unroll
            for (int mf = 0; mf < 8; ++mf)
#pragma unroll
                for (int nf = 0; nf < 2; ++nf) {
                    const int co = ncol*32 + nf*16 + lr;
                    const int p0 = mf*16 + (kg << 2);
                    *(f32x4*)&pl[co*132 + p0] = acc[mf][nf];
                }
        }
        __syncthreads();

        // ---- spline for row 2g+r: 6 ch x 128 px = 768 items, 3 per thread ----
#pragma unroll
        for (int ks = 0; ks < 3; ++ks) {
            const int c = __builtin_amdgcn_readfirstlane(t7 + 2*ks);
            const float xraw = (r == 0) ? (ks == 0 ? xr0 : ks == 1 ? xr1 : xr2)
                                        : (ks == 0 ? xr3 : ks == 1 ? xr4 : xr5);

            float u[9];
#pragma unroll
            for (int j = 0; j < 9; ++j) u[j] = pl[(c*9 + j)*132 + px] + b3[c*9 + j];

            bool inside = (xraw >= -1.f) && (xraw <= 1.f);
            float xc = fminf(fmaxf(xraw, -1.f), 1.f);
            float in01 = (xc + 1.f) * 0.5f;

            float m = u[0];
#pragma unroll
            for (int i2 = 1; i2 < 5; ++i2) m = fmaxf(m, u[i2]);
            float e[5], es = 0.f;
#pragma unroll
            for (int i2 = 0; i2 < 5; ++i2) { e[i2] = expf(u[i2] - m); es += e[i2]; }
            float wdt[5];
#pragma unroll
            for (int i2 = 0; i2 < 5; ++i2) wdt[i2] = 0.001f + (1.f - 0.001f*NB) * (e[i2] / es);

            float eh[4];
#pragma unroll
            for (int i2 = 0; i2 < 4; ++i2) eh[i2] = expf(u[5 + i2]);

            float first_w = 0.5f * wdt[0], last_w = 0.5f * wdt[4];
            float numer = 0.5f*first_w*eh[0] + 0.5f*last_w*eh[3]
                        + 0.5f*(eh[0]+eh[1])*wdt[1]
                        + 0.5f*(eh[1]+eh[2])*wdt[2]
                        + 0.5f*(eh[2]+eh[3])*wdt[3];
            float cst = numer / (1.f - 0.5f*first_w - 0.5f*last_w);

            float kn[6] = {cst, eh[0], eh[1], eh[2], eh[3], cst};
            float area = 0.f;
#pragma unroll
            for (int i2 = 0; i2 < 5; ++i2) area += 0.5f*(kn[i2]+kn[i2+1])*wdt[i2];
            float hts[6];
#pragma unroll
            for (int i2 = 0; i2 < 6; ++i2) hts[i2] = 0.001f + (1.f - 0.001f) * (kn[i2] / area);

            float C[6]; C[0] = 0.f;
#pragma unroll
            for (int i2 = 0; i2 < 5; ++i2) C[i2+1] = C[i2] + 0.5f*(hts[i2]+hts[i2+1])*wdt[i2];
            C[5] = 1.f;
            float L[6]; L[0] = 0.f;
#pragma unroll
            for (int i2 = 0; i2 < 5; ++i2) L[i2+1] = L[i2] + wdt[i2];
            L[5] = 1.f;

            int idx = 0;
#pragma unroll
            for (int i2 = 1; i2 < 6; ++i2) idx += (in01 >= L[i2]) ? 1 : 0;
            idx = min(idx, 4);

            float loc = L[0], cdf = C[0], hl = hts[0], hr = hts[1], wb2 = wdt[0];
#pragma unroll
            for (int i2 = 1; i2 < 5; ++i2) {
                if (i2 == idx) { loc = L[i2]; cdf = C[i2]; hl = hts[i2]; hr = hts[i2+1]; wb2 = wdt[i2]; }
            }

            float alpha = (in01 - loc) / wb2;
            float aa = 0.5f*(hr - hl)*wb2;
            float bb = hl*wb2;
            float o = fminf(fmaxf(aa*alpha*alpha + bb*alpha + cdf, 0.f), 1.f);
            float sl = logf(alpha*(hr - hl) + hl);
            float outv = o*2.f - 1.f;
            if (!inside) { outv = xraw; sl = 0.f; }
            out[((size_t)(b*CFULL + CH + c)*HH + (2*g + r))*WW + px] = outv;
            lad += sl;
        }
    }

#pragma unroll
    for (int off = 32; off > 0; off >>= 1) lad += __shfl_down(lad, off, 64);
    if ((tid & 63) == 0) red[tid >> 6] = lad;
    __syncthreads();
    if (tid == 0) {
        float s = red[0] + red[1] + red[2] + red[3];
        atomicAdd(&obj[b], s);
    }
}

extern "C" void kernel_launch(void* const* d_in, const int* in_sizes, int n_in,
                              void* d_out, int out_size, void* d_ws, size_t ws_size,
                              hipStream_t stream) {
    const float* x   = (const float*)d_in[0];
    const float* obj = (const float*)d_in[1];
    const float* w1  = (const float*)d_in[2];
    const float* b1  = (const float*)d_in[3];
    const float* w2  = (const float*)d_in[4];
    const float* b2  = (const float*)d_in[5];
    const float* w3  = (const float*)d_in[6];
    const float* b3  = (const float*)d_in[7];

    float* out_t = (float*)d_out;
    float* obj_o = out_t + OUT_ELEMS;
    ushort* h2  = (ushort*)d_ws;
    ushort* W3f = (ushort*)((char*)d_ws + H2_BYTES);
    ushort* W1f = (ushort*)((char*)d_ws + H2_BYTES + 147456);
    ushort* W2f = (ushort*)((char*)d_ws + H2_BYTES + 147456 + 16384);

    const int prep_items = WFRAG_ELEMS + W1F_ELEMS + W2F_ELEMS;   // 98304
    k_prep_all<<<(prep_items + 255)/256, 256, 0, stream>>>(w1, w2, w3, obj, obj_o, W1f, W2f, W3f);
    k_conv12<<<B*HH, 256, 0, stream>>>(x, W1f, b1, W2f, b2, h2);
    k_conv3_spline<<<dim3(HH/2, B), 256, 0, stream>>>(x, h2, W3f, b3, out_t, obj_o);
}